// Round 1
// baseline (826.392 us; speedup 1.0000x reference)
//
#include <hip/hip_runtime.h>

#define N_NODES 100000
#define N_EDGES 1600000
#define E_TOT   (N_EDGES + N_NODES)
#define NEG_SLOPE 0.2f

__device__ __forceinline__ float lrelu(float v) { return v > 0.f ? v : NEG_SLOPE * v; }

// ---- CSR build: degree count ----
__global__ void k_deg(const int* __restrict__ ei, int* __restrict__ deg) {
    int t = blockIdx.x * blockDim.x + threadIdx.x;
    if (t >= E_TOT) return;
    int d = (t < N_EDGES) ? ei[N_EDGES + t] : (t - N_EDGES);
    atomicAdd(&deg[d], 1);
}

// ---- CSR build: single-block exclusive scan over 100K degrees ----
__global__ __launch_bounds__(1024) void k_scan(const int* __restrict__ deg,
                                               int* __restrict__ rowptr) {
    const int T = 1024;
    int t = threadIdx.x;
    const int chunk = (N_NODES + T - 1) / T;  // 98
    int b = t * chunk;
    int e = min(b + chunk, N_NODES);
    int sum = 0;
    for (int i = b; i < e; ++i) sum += deg[i];
    __shared__ int ps[T];
    ps[t] = sum;
    __syncthreads();
    for (int off = 1; off < T; off <<= 1) {
        int v = (t >= off) ? ps[t - off] : 0;
        __syncthreads();
        ps[t] += v;
        __syncthreads();
    }
    int base = (t == 0) ? 0 : ps[t - 1];
    for (int i = b; i < e; ++i) { rowptr[i] = base; base += deg[i]; }
    if (t == T - 1) rowptr[N_NODES] = ps[T - 1];
}

// ---- CSR build: scatter src ids into per-dst lists ----
__global__ void k_scatter(const int* __restrict__ ei, const int* __restrict__ rowptr,
                          int* __restrict__ cursor, int* __restrict__ col) {
    int t = blockIdx.x * blockDim.x + threadIdx.x;
    if (t >= E_TOT) return;
    int s, d;
    if (t < N_EDGES) { s = ei[t]; d = ei[N_EDGES + t]; }
    else             { s = t - N_EDGES; d = s; }
    int pos = rowptr[d] + atomicAdd(&cursor[d], 1);
    col[pos] = s;
}

// ---- Layer 1 GEMM: h1 = x @ W1 (128x128), fused attention logits ----
// block = 128 threads = 4 nodes x 32 lanes; each thread computes 4 consecutive outputs
__global__ __launch_bounds__(128) void k_gemm1(const float* __restrict__ x,
                                               const float* __restrict__ W1,
                                               const float* __restrict__ a_src,
                                               const float* __restrict__ a_dst,
                                               float* __restrict__ h1,
                                               float* __restrict__ als,
                                               float* __restrict__ ald) {
    __shared__ float xs[4 * 128];
    int t = threadIdx.x;
    int r = t >> 5, c = t & 31;
    size_t base = (size_t)blockIdx.x * 4 * 128;
#pragma unroll
    for (int i = 0; i < 4; ++i) xs[t + i * 128] = x[base + t + i * 128];
    __syncthreads();
    const float4* W1v = (const float4*)W1;
    float4 acc = make_float4(0.f, 0.f, 0.f, 0.f);
    const float* xr = &xs[r * 128];
#pragma unroll 8
    for (int k = 0; k < 128; ++k) {
        float xv = xr[k];
        float4 w = W1v[k * 32 + c];
        acc.x = fmaf(xv, w.x, acc.x);
        acc.y = fmaf(xv, w.y, acc.y);
        acc.z = fmaf(xv, w.z, acc.z);
        acc.w = fmaf(xv, w.w, acc.w);
    }
    int n = blockIdx.x * 4 + r;
    ((float4*)h1)[(size_t)n * 32 + c] = acc;
    // attention logits: a_src/a_dst are (4,32) contiguous = 128 floats, indexed by j=c*4+i
    float4 as4 = ((const float4*)a_src)[c];
    float4 ad4 = ((const float4*)a_dst)[c];
    float vs = acc.x * as4.x + acc.y * as4.y + acc.z * as4.z + acc.w * as4.w;
    float vd = acc.x * ad4.x + acc.y * ad4.y + acc.z * ad4.z + acc.w * ad4.w;
#pragma unroll
    for (int off = 4; off >= 1; off >>= 1) {
        vs += __shfl_down(vs, off, 8);
        vd += __shfl_down(vd, off, 8);
    }
    if ((c & 7) == 0) {
        int h = c >> 3;
        als[n * 4 + h] = vs;
        ald[n * 4 + h] = vd;
    }
}

// ---- Layer 1 aggregation: pull-based segment softmax + weighted sum ----
// block = 128 threads = 1 node; thread j owns channel j (head h = j>>5)
__global__ __launch_bounds__(128) void k_agg1(const float* __restrict__ h1,
                                              const float* __restrict__ als,
                                              const float* __restrict__ ald,
                                              const int* __restrict__ rowptr,
                                              const int* __restrict__ col,
                                              const float* __restrict__ b1,
                                              float* __restrict__ out1) {
    int n = blockIdx.x;
    int j = threadIdx.x;
    int h = j >> 5;
    int cl = j & 31;
    __shared__ int scol[32];
    __shared__ float sex[128];
    float ad = ald[n * 4 + h];
    int beg = rowptr[n], end = rowptr[n + 1];
    float acc = 0.f, den = 0.f;
    for (int base = beg; base < end; base += 32) {
        int cnt = min(32, end - base);
        __syncthreads();  // protect previous chunk's LDS from overwrite
        if (j < cnt) scol[j] = col[base + j];
        __syncthreads();
        if (cl < cnt) {
            int s = scol[cl];
            sex[h * 32 + cl] = __expf(lrelu(als[s * 4 + h] + ad));
        }
        __syncthreads();
        for (int q = 0; q < cnt; ++q) {
            float ex = sex[h * 32 + q];
            int s = scol[q];
            acc = fmaf(ex, h1[(size_t)s * 128 + j], acc);
            den += ex;
        }
    }
    out1[(size_t)n * 128 + j] = fmaxf(acc / den + b1[j], 0.f);
}

// ---- Layer 2 GEMM: h2 = relu_out1 @ W2 (128x16), fused logits ----
// block = 256 threads = 16 nodes x 16 lanes
__global__ __launch_bounds__(256) void k_gemm2(const float* __restrict__ out1,
                                               const float* __restrict__ W2,
                                               const float* __restrict__ a_src,
                                               const float* __restrict__ a_dst,
                                               float* __restrict__ h2,
                                               float* __restrict__ als,
                                               float* __restrict__ ald) {
    __shared__ float W2s[128 * 16];
    __shared__ float xs[16 * 132];  // +4 pad per row to break bank aliasing
    int t = threadIdx.x;
#pragma unroll
    for (int i = 0; i < 8; ++i) W2s[t + i * 256] = W2[t + i * 256];
    size_t base = (size_t)blockIdx.x * 16 * 128;
#pragma unroll
    for (int i = 0; i < 8; ++i) {
        int idx = t + i * 256;
        xs[(idx >> 7) * 132 + (idx & 127)] = out1[base + idx];
    }
    __syncthreads();
    int r = t >> 4, c = t & 15;
    float acc = 0.f;
    const float* xr = &xs[r * 132];
#pragma unroll 8
    for (int k = 0; k < 128; ++k) acc = fmaf(xr[k], W2s[k * 16 + c], acc);
    int n = blockIdx.x * 16 + r;
    h2[(size_t)n * 16 + c] = acc;
    float vs = acc * a_src[c];
    float vd = acc * a_dst[c];
#pragma unroll
    for (int off = 8; off >= 1; off >>= 1) {
        vs += __shfl_down(vs, off, 16);
        vd += __shfl_down(vd, off, 16);
    }
    if (c == 0) { als[n] = vs; ald[n] = vd; }
}

// ---- Layer 2 aggregation: wave per node, 4 edge-slots x 16 channels ----
__global__ __launch_bounds__(256) void k_agg2(const float* __restrict__ h2,
                                              const float* __restrict__ als,
                                              const float* __restrict__ ald,
                                              const int* __restrict__ rowptr,
                                              const int* __restrict__ col,
                                              const float* __restrict__ b2,
                                              float* __restrict__ out) {
    int wave = threadIdx.x >> 6;
    int lane = threadIdx.x & 63;
    int n = blockIdx.x * 4 + wave;
    int c = lane & 15, slot = lane >> 4;
    float ad = ald[n];
    int beg = rowptr[n], end = rowptr[n + 1];
    float acc = 0.f, den = 0.f;
    for (int idx = beg + slot; idx < end; idx += 4) {
        int s = col[idx];
        float ex = __expf(lrelu(als[s] + ad));
        acc = fmaf(ex, h2[(size_t)s * 16 + c], acc);
        den += ex;
    }
    acc += __shfl_xor(acc, 16, 64); den += __shfl_xor(den, 16, 64);
    acc += __shfl_xor(acc, 32, 64); den += __shfl_xor(den, 32, 64);
    if (slot == 0) out[(size_t)n * 16 + c] = acc / den + b2[c];
}

extern "C" void kernel_launch(void* const* d_in, const int* in_sizes, int n_in,
                              void* d_out, int out_size, void* d_ws, size_t ws_size,
                              hipStream_t stream) {
    const float* x   = (const float*)d_in[0];
    const int*   ei  = (const int*)d_in[1];
    const float* W1  = (const float*)d_in[2];
    const float* as1 = (const float*)d_in[3];
    const float* ad1 = (const float*)d_in[4];
    const float* b1  = (const float*)d_in[5];
    const float* W2  = (const float*)d_in[6];
    const float* as2 = (const float*)d_in[7];
    const float* ad2 = (const float*)d_in[8];
    const float* b2  = (const float*)d_in[9];
    float* out = (float*)d_out;

    char* ws = (char*)d_ws;
    size_t off = 0;
    auto alloc = [&](size_t bytes) -> void* {
        void* p = ws + off;
        off += (bytes + 255) & ~(size_t)255;
        return p;
    };
    float* h1    = (float*)alloc((size_t)N_NODES * 128 * 4);
    float* out1  = (float*)alloc((size_t)N_NODES * 128 * 4);
    float* als1v = (float*)alloc((size_t)N_NODES * 4 * 4);
    float* ald1v = (float*)alloc((size_t)N_NODES * 4 * 4);
    float* h2    = (float*)alloc((size_t)N_NODES * 16 * 4);
    float* als2v = (float*)alloc((size_t)N_NODES * 4);
    float* ald2v = (float*)alloc((size_t)N_NODES * 4);
    int* deg     = (int*)alloc((size_t)N_NODES * 4);
    int* rowptr  = (int*)alloc((size_t)(N_NODES + 1) * 4);
    int* cursor  = (int*)alloc((size_t)N_NODES * 4);
    int* colA    = (int*)alloc((size_t)E_TOT * 4);

    hipMemsetAsync(deg, 0, (size_t)N_NODES * 4, stream);
    hipMemsetAsync(cursor, 0, (size_t)N_NODES * 4, stream);

    k_deg<<<(E_TOT + 255) / 256, 256, 0, stream>>>(ei, deg);
    k_scan<<<1, 1024, 0, stream>>>(deg, rowptr);
    k_scatter<<<(E_TOT + 255) / 256, 256, 0, stream>>>(ei, rowptr, cursor, colA);
    k_gemm1<<<N_NODES / 4, 128, 0, stream>>>(x, W1, as1, ad1, h1, als1v, ald1v);
    k_agg1<<<N_NODES, 128, 0, stream>>>(h1, als1v, ald1v, rowptr, colA, b1, out1);
    k_gemm2<<<N_NODES / 16, 256, 0, stream>>>(out1, W2, as2, ad2, h2, als2v, ald2v);
    k_agg2<<<N_NODES / 4, 256, 0, stream>>>(h2, als2v, ald2v, rowptr, colA, b2, out);
}

// Round 2
// 676.856 us; speedup vs baseline: 1.2209x; 1.2209x over previous
//
#include <hip/hip_runtime.h>

#define N_NODES 100000
#define N_EDGES 1600000
#define E_TOT   (N_EDGES + N_NODES)
#define NEG_SLOPE 0.2f

__device__ __forceinline__ float lrelu(float v) { return v > 0.f ? v : NEG_SLOPE * v; }

// ---- CSR build: degree count ----
__global__ void k_deg(const int* __restrict__ ei, int* __restrict__ deg) {
    int t = blockIdx.x * blockDim.x + threadIdx.x;
    if (t >= E_TOT) return;
    int d = (t < N_EDGES) ? ei[N_EDGES + t] : (t - N_EDGES);
    atomicAdd(&deg[d], 1);
}

// ---- CSR build: single-block exclusive scan over 100K degrees ----
__global__ __launch_bounds__(1024) void k_scan(const int* __restrict__ deg,
                                               int* __restrict__ rowptr) {
    const int T = 1024;
    int t = threadIdx.x;
    const int chunk = (N_NODES + T - 1) / T;  // 98
    int b = t * chunk;
    int e = min(b + chunk, N_NODES);
    int sum = 0;
    for (int i = b; i < e; ++i) sum += deg[i];
    __shared__ int ps[T];
    ps[t] = sum;
    __syncthreads();
    for (int off = 1; off < T; off <<= 1) {
        int v = (t >= off) ? ps[t - off] : 0;
        __syncthreads();
        ps[t] += v;
        __syncthreads();
    }
    int base = (t == 0) ? 0 : ps[t - 1];
    for (int i = b; i < e; ++i) { rowptr[i] = base; base += deg[i]; }
    if (t == T - 1) rowptr[N_NODES] = ps[T - 1];
}

// ---- CSR build: scatter src ids into per-dst lists ----
__global__ void k_scatter(const int* __restrict__ ei, const int* __restrict__ rowptr,
                          int* __restrict__ cursor, int* __restrict__ col) {
    int t = blockIdx.x * blockDim.x + threadIdx.x;
    if (t >= E_TOT) return;
    int s, d;
    if (t < N_EDGES) { s = ei[t]; d = ei[N_EDGES + t]; }
    else             { s = t - N_EDGES; d = s; }
    int pos = rowptr[d] + atomicAdd(&cursor[d], 1);
    col[pos] = s;
}

// ---- Layer 1 GEMM: h1 = x @ W1 (128x128), fused attention logits ----
// block = 256 threads, 64 nodes/block. Thread (rg,c): rg=t>>5 in [0,8), c=t&31.
// Each thread accumulates 8 nodes (rg+8i) x float4 output column c.
// One W float4 load now feeds 64 FLOP (was 8) -> L2 W-traffic /8.
__global__ __launch_bounds__(256) void k_gemm1(const float* __restrict__ x,
                                               const float* __restrict__ W1,
                                               const float* __restrict__ a_src,
                                               const float* __restrict__ a_dst,
                                               float* __restrict__ h1,
                                               float* __restrict__ als,
                                               float* __restrict__ ald) {
    __shared__ float xs[64 * 128];  // 32 KB
    int t = threadIdx.x;
    int c = t & 31, rg = t >> 5;
    int nb = blockIdx.x * 64;
    // stage x tile: 2048 float4s, 8 per thread, coalesced; guard tail block
    const float4* xv4 = (const float4*)x;
    float4* xs4 = (float4*)xs;
    size_t base4 = (size_t)nb * 32;
    const size_t lim4 = (size_t)N_NODES * 32;
#pragma unroll
    for (int i = 0; i < 8; ++i) {
        size_t g = base4 + t + i * 256;
        if (g < lim4) xs4[t + i * 256] = xv4[g];
    }
    __syncthreads();
    const float4* W1v = (const float4*)W1;
    float4 acc[8];
#pragma unroll
    for (int i = 0; i < 8; ++i) acc[i] = make_float4(0.f, 0.f, 0.f, 0.f);
#pragma unroll 4
    for (int k = 0; k < 128; ++k) {
        float4 w = W1v[k * 32 + c];
#pragma unroll
        for (int i = 0; i < 8; ++i) {
            float xv = xs[(rg + 8 * i) * 128 + k];  // broadcast across 32 c-lanes
            acc[i].x = fmaf(xv, w.x, acc[i].x);
            acc[i].y = fmaf(xv, w.y, acc[i].y);
            acc[i].z = fmaf(xv, w.z, acc[i].z);
            acc[i].w = fmaf(xv, w.w, acc[i].w);
        }
    }
    float4 as4 = ((const float4*)a_src)[c];
    float4 ad4 = ((const float4*)a_dst)[c];
#pragma unroll
    for (int i = 0; i < 8; ++i) {
        int n = nb + rg + 8 * i;
        if (n < N_NODES) ((float4*)h1)[(size_t)n * 32 + c] = acc[i];
        float vs = acc[i].x * as4.x + acc[i].y * as4.y + acc[i].z * as4.z + acc[i].w * as4.w;
        float vd = acc[i].x * ad4.x + acc[i].y * ad4.y + acc[i].z * ad4.z + acc[i].w * ad4.w;
        vs += __shfl_down(vs, 4, 8); vs += __shfl_down(vs, 2, 8); vs += __shfl_down(vs, 1, 8);
        vd += __shfl_down(vd, 4, 8); vd += __shfl_down(vd, 2, 8); vd += __shfl_down(vd, 1, 8);
        if ((c & 7) == 0 && n < N_NODES) {
            int h = c >> 3;
            als[n * 4 + h] = vs;
            ald[n * 4 + h] = vd;
        }
    }
}

// ---- Layer 1 aggregation: pull-based segment softmax + weighted sum ----
// block = 128 threads = 1 node; thread j owns channel j (head h = j>>5)
__global__ __launch_bounds__(128) void k_agg1(const float* __restrict__ h1,
                                              const float* __restrict__ als,
                                              const float* __restrict__ ald,
                                              const int* __restrict__ rowptr,
                                              const int* __restrict__ col,
                                              const float* __restrict__ b1,
                                              float* __restrict__ out1) {
    int n = blockIdx.x;
    int j = threadIdx.x;
    int h = j >> 5;
    int cl = j & 31;
    __shared__ int scol[32];
    __shared__ float sex[128];
    float ad = ald[n * 4 + h];
    int beg = rowptr[n], end = rowptr[n + 1];
    float acc = 0.f, den = 0.f;
    for (int base = beg; base < end; base += 32) {
        int cnt = min(32, end - base);
        __syncthreads();  // protect previous chunk's LDS from overwrite
        if (j < cnt) scol[j] = col[base + j];
        __syncthreads();
        if (cl < cnt) {
            int s = scol[cl];
            sex[h * 32 + cl] = __expf(lrelu(als[s * 4 + h] + ad));
        }
        __syncthreads();
        for (int q = 0; q < cnt; ++q) {
            float ex = sex[h * 32 + q];
            int s = scol[q];
            acc = fmaf(ex, h1[(size_t)s * 128 + j], acc);
            den += ex;
        }
    }
    out1[(size_t)n * 128 + j] = fmaxf(acc / den + b1[j], 0.f);
}

// ---- Layer 2 GEMM: h2 = relu_out1 @ W2 (128x16), fused logits ----
// block = 256 threads = 16 nodes x 16 lanes
__global__ __launch_bounds__(256) void k_gemm2(const float* __restrict__ out1,
                                               const float* __restrict__ W2,
                                               const float* __restrict__ a_src,
                                               const float* __restrict__ a_dst,
                                               float* __restrict__ h2,
                                               float* __restrict__ als,
                                               float* __restrict__ ald) {
    __shared__ float W2s[128 * 16];
    __shared__ float xs[16 * 132];  // +4 pad per row to break bank aliasing
    int t = threadIdx.x;
#pragma unroll
    for (int i = 0; i < 8; ++i) W2s[t + i * 256] = W2[t + i * 256];
    size_t base = (size_t)blockIdx.x * 16 * 128;
#pragma unroll
    for (int i = 0; i < 8; ++i) {
        int idx = t + i * 256;
        xs[(idx >> 7) * 132 + (idx & 127)] = out1[base + idx];
    }
    __syncthreads();
    int r = t >> 4, c = t & 15;
    float acc = 0.f;
    const float* xr = &xs[r * 132];
#pragma unroll 8
    for (int k = 0; k < 128; ++k) acc = fmaf(xr[k], W2s[k * 16 + c], acc);
    int n = blockIdx.x * 16 + r;
    h2[(size_t)n * 16 + c] = acc;
    float vs = acc * a_src[c];
    float vd = acc * a_dst[c];
#pragma unroll
    for (int off = 8; off >= 1; off >>= 1) {
        vs += __shfl_down(vs, off, 16);
        vd += __shfl_down(vd, off, 16);
    }
    if (c == 0) { als[n] = vs; ald[n] = vd; }
}

// ---- Layer 2 aggregation: wave per node, 4 edge-slots x 16 channels ----
__global__ __launch_bounds__(256) void k_agg2(const float* __restrict__ h2,
                                              const float* __restrict__ als,
                                              const float* __restrict__ ald,
                                              const int* __restrict__ rowptr,
                                              const int* __restrict__ col,
                                              const float* __restrict__ b2,
                                              float* __restrict__ out) {
    int wave = threadIdx.x >> 6;
    int lane = threadIdx.x & 63;
    int n = blockIdx.x * 4 + wave;
    int c = lane & 15, slot = lane >> 4;
    float ad = ald[n];
    int beg = rowptr[n], end = rowptr[n + 1];
    float acc = 0.f, den = 0.f;
    for (int idx = beg + slot; idx < end; idx += 4) {
        int s = col[idx];
        float ex = __expf(lrelu(als[s] + ad));
        acc = fmaf(ex, h2[(size_t)s * 16 + c], acc);
        den += ex;
    }
    acc += __shfl_xor(acc, 16, 64); den += __shfl_xor(den, 16, 64);
    acc += __shfl_xor(acc, 32, 64); den += __shfl_xor(den, 32, 64);
    if (slot == 0) out[(size_t)n * 16 + c] = acc / den + b2[c];
}

extern "C" void kernel_launch(void* const* d_in, const int* in_sizes, int n_in,
                              void* d_out, int out_size, void* d_ws, size_t ws_size,
                              hipStream_t stream) {
    const float* x   = (const float*)d_in[0];
    const int*   ei  = (const int*)d_in[1];
    const float* W1  = (const float*)d_in[2];
    const float* as1 = (const float*)d_in[3];
    const float* ad1 = (const float*)d_in[4];
    const float* b1  = (const float*)d_in[5];
    const float* W2  = (const float*)d_in[6];
    const float* as2 = (const float*)d_in[7];
    const float* ad2 = (const float*)d_in[8];
    const float* b2  = (const float*)d_in[9];
    float* out = (float*)d_out;

    char* ws = (char*)d_ws;
    size_t off = 0;
    auto alloc = [&](size_t bytes) -> void* {
        void* p = ws + off;
        off += (bytes + 255) & ~(size_t)255;
        return p;
    };
    float* h1    = (float*)alloc((size_t)N_NODES * 128 * 4);
    float* out1  = (float*)alloc((size_t)N_NODES * 128 * 4);
    float* als1v = (float*)alloc((size_t)N_NODES * 4 * 4);
    float* ald1v = (float*)alloc((size_t)N_NODES * 4 * 4);
    float* h2    = (float*)alloc((size_t)N_NODES * 16 * 4);
    float* als2v = (float*)alloc((size_t)N_NODES * 4);
    float* ald2v = (float*)alloc((size_t)N_NODES * 4);
    int* deg     = (int*)alloc((size_t)N_NODES * 4);
    int* rowptr  = (int*)alloc((size_t)(N_NODES + 1) * 4);
    int* cursor  = (int*)alloc((size_t)N_NODES * 4);
    int* colA    = (int*)alloc((size_t)E_TOT * 4);

    hipMemsetAsync(deg, 0, (size_t)N_NODES * 4, stream);
    hipMemsetAsync(cursor, 0, (size_t)N_NODES * 4, stream);

    k_deg<<<(E_TOT + 255) / 256, 256, 0, stream>>>(ei, deg);
    k_scan<<<1, 1024, 0, stream>>>(deg, rowptr);
    k_scatter<<<(E_TOT + 255) / 256, 256, 0, stream>>>(ei, rowptr, cursor, colA);
    k_gemm1<<<(N_NODES + 63) / 64, 256, 0, stream>>>(x, W1, as1, ad1, h1, als1v, ald1v);
    k_agg1<<<N_NODES, 128, 0, stream>>>(h1, als1v, ald1v, rowptr, colA, b1, out1);
    k_gemm2<<<N_NODES / 16, 256, 0, stream>>>(out1, W2, as2, ad2, h2, als2v, ald2v);
    k_agg2<<<N_NODES / 4, 256, 0, stream>>>(h2, als2v, ald2v, rowptr, colA, b2, out);
}

// Round 3
// 536.438 us; speedup vs baseline: 1.5405x; 1.2618x over previous
//
#include <hip/hip_runtime.h>

#define N_NODES 100000
#define N_EDGES 1600000
#define E_TOT   (N_EDGES + N_NODES)
#define NEG_SLOPE 0.2f
#define SCAN_B  98   // ceil(N_NODES / 1024)

__device__ __forceinline__ float lrelu(float v) { return v > 0.f ? v : NEG_SLOPE * v; }

// ---- CSR build: degree count ----
__global__ void k_deg(const int* __restrict__ ei, int* __restrict__ deg) {
    int t = blockIdx.x * blockDim.x + threadIdx.x;
    if (t >= E_TOT) return;
    int d = (t < N_EDGES) ? ei[N_EDGES + t] : (t - N_EDGES);
    atomicAdd(&deg[d], 1);
}

// ---- hierarchical scan, phase 1: block-local exclusive scan + block totals ----
__global__ __launch_bounds__(1024) void k_scan1(const int* __restrict__ deg,
                                                int* __restrict__ rowptr,
                                                int* __restrict__ bsum) {
    int t = threadIdx.x;
    int g = blockIdx.x * 1024 + t;
    int d = (g < N_NODES) ? deg[g] : 0;
    __shared__ int ps[1024];
    ps[t] = d;
    __syncthreads();
    for (int off = 1; off < 1024; off <<= 1) {
        int v = (t >= off) ? ps[t - off] : 0;
        __syncthreads();
        ps[t] += v;
        __syncthreads();
    }
    if (g < N_NODES) rowptr[g] = ps[t] - d;   // exclusive within block
    if (t == 1023) bsum[blockIdx.x] = ps[t];
}

// ---- phase 2: scan the 98 block totals (tiny) ----
__global__ __launch_bounds__(128) void k_scan2(int* __restrict__ bsum) {
    int t = threadIdx.x;
    int v = (t < SCAN_B) ? bsum[t] : 0;
    __shared__ int ps[128];
    ps[t] = v;
    __syncthreads();
    for (int off = 1; off < 128; off <<= 1) {
        int u = (t >= off) ? ps[t - off] : 0;
        __syncthreads();
        ps[t] += u;
        __syncthreads();
    }
    if (t < SCAN_B) bsum[t] = ps[t] - v;      // exclusive block offsets
}

// ---- phase 3: add block offsets ----
__global__ __launch_bounds__(1024) void k_scan3(int* __restrict__ rowptr,
                                                const int* __restrict__ bsum) {
    int g = blockIdx.x * 1024 + threadIdx.x;
    if (g < N_NODES) rowptr[g] += bsum[blockIdx.x];
    if (g == 0) rowptr[N_NODES] = E_TOT;      // total is statically known
}

// ---- CSR build: scatter src ids into per-dst lists ----
__global__ void k_scatter(const int* __restrict__ ei, const int* __restrict__ rowptr,
                          int* __restrict__ cursor, int* __restrict__ col) {
    int t = blockIdx.x * blockDim.x + threadIdx.x;
    if (t >= E_TOT) return;
    int s, d;
    if (t < N_EDGES) { s = ei[t]; d = ei[N_EDGES + t]; }
    else             { s = t - N_EDGES; d = s; }
    int pos = rowptr[d] + atomicAdd(&cursor[d], 1);
    col[pos] = s;
}

// ---- Layer 1 GEMM: h1 = x @ W1 (128x128), fused attention logits ----
// block = 256 threads, 64 nodes/block; each thread: 8 nodes x float4 column.
__global__ __launch_bounds__(256) void k_gemm1(const float* __restrict__ x,
                                               const float* __restrict__ W1,
                                               const float* __restrict__ a_src,
                                               const float* __restrict__ a_dst,
                                               float* __restrict__ h1,
                                               float* __restrict__ als,
                                               float* __restrict__ ald) {
    __shared__ float xs[64 * 128];  // 32 KB
    int t = threadIdx.x;
    int c = t & 31, rg = t >> 5;
    int nb = blockIdx.x * 64;
    const float4* xv4 = (const float4*)x;
    float4* xs4 = (float4*)xs;
    size_t base4 = (size_t)nb * 32;
    const size_t lim4 = (size_t)N_NODES * 32;
#pragma unroll
    for (int i = 0; i < 8; ++i) {
        size_t g = base4 + t + i * 256;
        if (g < lim4) xs4[t + i * 256] = xv4[g];
    }
    __syncthreads();
    const float4* W1v = (const float4*)W1;
    float4 acc[8];
#pragma unroll
    for (int i = 0; i < 8; ++i) acc[i] = make_float4(0.f, 0.f, 0.f, 0.f);
#pragma unroll 4
    for (int k = 0; k < 128; ++k) {
        float4 w = W1v[k * 32 + c];
#pragma unroll
        for (int i = 0; i < 8; ++i) {
            float xv = xs[(rg + 8 * i) * 128 + k];  // broadcast across c-lanes
            acc[i].x = fmaf(xv, w.x, acc[i].x);
            acc[i].y = fmaf(xv, w.y, acc[i].y);
            acc[i].z = fmaf(xv, w.z, acc[i].z);
            acc[i].w = fmaf(xv, w.w, acc[i].w);
        }
    }
    float4 as4 = ((const float4*)a_src)[c];
    float4 ad4 = ((const float4*)a_dst)[c];
#pragma unroll
    for (int i = 0; i < 8; ++i) {
        int n = nb + rg + 8 * i;
        if (n < N_NODES) ((float4*)h1)[(size_t)n * 32 + c] = acc[i];
        float vs = acc[i].x * as4.x + acc[i].y * as4.y + acc[i].z * as4.z + acc[i].w * as4.w;
        float vd = acc[i].x * ad4.x + acc[i].y * ad4.y + acc[i].z * ad4.z + acc[i].w * ad4.w;
        vs += __shfl_down(vs, 4, 8); vs += __shfl_down(vs, 2, 8); vs += __shfl_down(vs, 1, 8);
        vd += __shfl_down(vd, 4, 8); vd += __shfl_down(vd, 2, 8); vd += __shfl_down(vd, 1, 8);
        if ((c & 7) == 0 && n < N_NODES) {
            int h = c >> 3;
            als[n * 4 + h] = vs;
            ald[n * 4 + h] = vd;
        }
    }
}

// ---- Layer 1 aggregation: pull-based segment softmax + weighted sum ----
__global__ __launch_bounds__(128) void k_agg1(const float* __restrict__ h1,
                                              const float* __restrict__ als,
                                              const float* __restrict__ ald,
                                              const int* __restrict__ rowptr,
                                              const int* __restrict__ col,
                                              const float* __restrict__ b1,
                                              float* __restrict__ out1) {
    int n = blockIdx.x;
    int j = threadIdx.x;
    int h = j >> 5;
    int cl = j & 31;
    __shared__ int scol[32];
    __shared__ float sex[128];
    float ad = ald[n * 4 + h];
    int beg = rowptr[n], end = rowptr[n + 1];
    float acc = 0.f, den = 0.f;
    for (int base = beg; base < end; base += 32) {
        int cnt = min(32, end - base);
        __syncthreads();
        if (j < cnt) scol[j] = col[base + j];
        __syncthreads();
        if (cl < cnt) {
            int s = scol[cl];
            sex[h * 32 + cl] = __expf(lrelu(als[s * 4 + h] + ad));
        }
        __syncthreads();
        for (int q = 0; q < cnt; ++q) {
            float ex = sex[h * 32 + q];
            int s = scol[q];
            acc = fmaf(ex, h1[(size_t)s * 128 + j], acc);
            den += ex;
        }
    }
    out1[(size_t)n * 128 + j] = fmaxf(acc / den + b1[j], 0.f);
}

// ---- Layer 2 GEMM: h2 = relu_out1 @ W2 (128x16), fused logits ----
__global__ __launch_bounds__(256) void k_gemm2(const float* __restrict__ out1,
                                               const float* __restrict__ W2,
                                               const float* __restrict__ a_src,
                                               const float* __restrict__ a_dst,
                                               float* __restrict__ h2,
                                               float* __restrict__ als,
                                               float* __restrict__ ald) {
    __shared__ float W2s[128 * 16];
    __shared__ float xs[16 * 132];
    int t = threadIdx.x;
#pragma unroll
    for (int i = 0; i < 8; ++i) W2s[t + i * 256] = W2[t + i * 256];
    size_t base = (size_t)blockIdx.x * 16 * 128;
#pragma unroll
    for (int i = 0; i < 8; ++i) {
        int idx = t + i * 256;
        xs[(idx >> 7) * 132 + (idx & 127)] = out1[base + idx];
    }
    __syncthreads();
    int r = t >> 4, c = t & 15;
    float acc = 0.f;
    const float* xr = &xs[r * 132];
#pragma unroll 8
    for (int k = 0; k < 128; ++k) acc = fmaf(xr[k], W2s[k * 16 + c], acc);
    int n = blockIdx.x * 16 + r;
    h2[(size_t)n * 16 + c] = acc;
    float vs = acc * a_src[c];
    float vd = acc * a_dst[c];
#pragma unroll
    for (int off = 8; off >= 1; off >>= 1) {
        vs += __shfl_down(vs, off, 16);
        vd += __shfl_down(vd, off, 16);
    }
    if (c == 0) { als[n] = vs; ald[n] = vd; }
}

// ---- Layer 2 aggregation: wave per node, 4 edge-slots x 16 channels ----
__global__ __launch_bounds__(256) void k_agg2(const float* __restrict__ h2,
                                              const float* __restrict__ als,
                                              const float* __restrict__ ald,
                                              const int* __restrict__ rowptr,
                                              const int* __restrict__ col,
                                              const float* __restrict__ b2,
                                              float* __restrict__ out) {
    int wave = threadIdx.x >> 6;
    int lane = threadIdx.x & 63;
    int n = blockIdx.x * 4 + wave;
    int c = lane & 15, slot = lane >> 4;
    float ad = ald[n];
    int beg = rowptr[n], end = rowptr[n + 1];
    float acc = 0.f, den = 0.f;
    for (int idx = beg + slot; idx < end; idx += 4) {
        int s = col[idx];
        float ex = __expf(lrelu(als[s] + ad));
        acc = fmaf(ex, h2[(size_t)s * 16 + c], acc);
        den += ex;
    }
    acc += __shfl_xor(acc, 16, 64); den += __shfl_xor(den, 16, 64);
    acc += __shfl_xor(acc, 32, 64); den += __shfl_xor(den, 32, 64);
    if (slot == 0) out[(size_t)n * 16 + c] = acc / den + b2[c];
}

extern "C" void kernel_launch(void* const* d_in, const int* in_sizes, int n_in,
                              void* d_out, int out_size, void* d_ws, size_t ws_size,
                              hipStream_t stream) {
    const float* x   = (const float*)d_in[0];
    const int*   ei  = (const int*)d_in[1];
    const float* W1  = (const float*)d_in[2];
    const float* as1 = (const float*)d_in[3];
    const float* ad1 = (const float*)d_in[4];
    const float* b1  = (const float*)d_in[5];
    const float* W2  = (const float*)d_in[6];
    const float* as2 = (const float*)d_in[7];
    const float* ad2 = (const float*)d_in[8];
    const float* b2  = (const float*)d_in[9];
    float* out = (float*)d_out;

    char* ws = (char*)d_ws;
    size_t off = 0;
    auto alloc = [&](size_t bytes) -> void* {
        void* p = ws + off;
        off += (bytes + 255) & ~(size_t)255;
        return p;
    };
    float* h1    = (float*)alloc((size_t)N_NODES * 128 * 4);
    float* out1  = (float*)alloc((size_t)N_NODES * 128 * 4);
    float* als1v = (float*)alloc((size_t)N_NODES * 4 * 4);
    float* ald1v = (float*)alloc((size_t)N_NODES * 4 * 4);
    float* h2    = (float*)alloc((size_t)N_NODES * 16 * 4);
    float* als2v = (float*)alloc((size_t)N_NODES * 4);
    float* ald2v = (float*)alloc((size_t)N_NODES * 4);
    int* deg     = (int*)alloc((size_t)N_NODES * 4);
    int* rowptr  = (int*)alloc((size_t)(N_NODES + 1) * 4);
    int* cursor  = (int*)alloc((size_t)N_NODES * 4);
    int* bsum    = (int*)alloc((size_t)SCAN_B * 4);
    int* colA    = (int*)alloc((size_t)E_TOT * 4);

    hipMemsetAsync(deg, 0, (size_t)N_NODES * 4, stream);
    hipMemsetAsync(cursor, 0, (size_t)N_NODES * 4, stream);

    k_deg<<<(E_TOT + 255) / 256, 256, 0, stream>>>(ei, deg);
    k_scan1<<<SCAN_B, 1024, 0, stream>>>(deg, rowptr, bsum);
    k_scan2<<<1, 128, 0, stream>>>(bsum);
    k_scan3<<<SCAN_B, 1024, 0, stream>>>(rowptr, bsum);
    k_scatter<<<(E_TOT + 255) / 256, 256, 0, stream>>>(ei, rowptr, cursor, colA);
    k_gemm1<<<(N_NODES + 63) / 64, 256, 0, stream>>>(x, W1, as1, ad1, h1, als1v, ald1v);
    k_agg1<<<N_NODES, 128, 0, stream>>>(h1, als1v, ald1v, rowptr, colA, b1, out1);
    k_gemm2<<<N_NODES / 16, 256, 0, stream>>>(out1, W2, as2, ad2, h2, als2v, ald2v);
    k_agg2<<<N_NODES / 4, 256, 0, stream>>>(h2, als2v, ald2v, rowptr, colA, b2, out);
}

// Round 4
// 514.966 us; speedup vs baseline: 1.6048x; 1.0417x over previous
//
#include <hip/hip_runtime.h>

#define N_NODES 100000
#define N_EDGES 1600000
#define E_TOT   (N_EDGES + N_NODES)
#define NEG_SLOPE 0.2f
#define SCAN_B  98   // ceil(N_NODES / 1024)

__device__ __forceinline__ float lrelu(float v) { return v > 0.f ? v : NEG_SLOPE * v; }

__device__ __forceinline__ unsigned short bf16rn(float f) {
    unsigned u = __float_as_uint(f);
    return (unsigned short)((u + 0x7FFFu + ((u >> 16) & 1u)) >> 16);
}
__device__ __forceinline__ float bf16tof(unsigned short h) {
    return __uint_as_float((unsigned)h << 16);
}

// ---- CSR build: degree count ----
__global__ void k_deg(const int* __restrict__ ei, int* __restrict__ deg) {
    int t = blockIdx.x * blockDim.x + threadIdx.x;
    if (t >= E_TOT) return;
    int d = (t < N_EDGES) ? ei[N_EDGES + t] : (t - N_EDGES);
    atomicAdd(&deg[d], 1);
}

// ---- hierarchical scan, phase 1 ----
__global__ __launch_bounds__(1024) void k_scan1(const int* __restrict__ deg,
                                                int* __restrict__ rowptr,
                                                int* __restrict__ bsum) {
    int t = threadIdx.x;
    int g = blockIdx.x * 1024 + t;
    int d = (g < N_NODES) ? deg[g] : 0;
    __shared__ int ps[1024];
    ps[t] = d;
    __syncthreads();
    for (int off = 1; off < 1024; off <<= 1) {
        int v = (t >= off) ? ps[t - off] : 0;
        __syncthreads();
        ps[t] += v;
        __syncthreads();
    }
    if (g < N_NODES) rowptr[g] = ps[t] - d;
    if (t == 1023) bsum[blockIdx.x] = ps[t];
}

// ---- phase 2: scan 98 block totals ----
__global__ __launch_bounds__(128) void k_scan2(int* __restrict__ bsum) {
    int t = threadIdx.x;
    int v = (t < SCAN_B) ? bsum[t] : 0;
    __shared__ int ps[128];
    ps[t] = v;
    __syncthreads();
    for (int off = 1; off < 128; off <<= 1) {
        int u = (t >= off) ? ps[t - off] : 0;
        __syncthreads();
        ps[t] += u;
        __syncthreads();
    }
    if (t < SCAN_B) bsum[t] = ps[t] - v;
}

// ---- phase 3: add block offsets ----
__global__ __launch_bounds__(1024) void k_scan3(int* __restrict__ rowptr,
                                                const int* __restrict__ bsum) {
    int g = blockIdx.x * 1024 + threadIdx.x;
    if (g < N_NODES) rowptr[g] += bsum[blockIdx.x];
    if (g == 0) rowptr[N_NODES] = E_TOT;
}

// ---- CSR build: scatter ----
__global__ void k_scatter(const int* __restrict__ ei, const int* __restrict__ rowptr,
                          int* __restrict__ cursor, int* __restrict__ col) {
    int t = blockIdx.x * blockDim.x + threadIdx.x;
    if (t >= E_TOT) return;
    int s, d;
    if (t < N_EDGES) { s = ei[t]; d = ei[N_EDGES + t]; }
    else             { s = t - N_EDGES; d = s; }
    int pos = rowptr[d] + atomicAdd(&cursor[d], 1);
    col[pos] = s;
}

// ---- Layer 1 GEMM: h1(bf16) = x @ W1, fused attention logits ----
__global__ __launch_bounds__(256) void k_gemm1(const float* __restrict__ x,
                                               const float* __restrict__ W1,
                                               const float* __restrict__ a_src,
                                               const float* __restrict__ a_dst,
                                               unsigned short* __restrict__ h1b,
                                               float* __restrict__ als,
                                               float* __restrict__ ald) {
    __shared__ float xs[64 * 128];  // 32 KB
    int t = threadIdx.x;
    int c = t & 31, rg = t >> 5;
    int nb = blockIdx.x * 64;
    const float4* xv4 = (const float4*)x;
    float4* xs4 = (float4*)xs;
    size_t base4 = (size_t)nb * 32;
    const size_t lim4 = (size_t)N_NODES * 32;
#pragma unroll
    for (int i = 0; i < 8; ++i) {
        size_t g = base4 + t + i * 256;
        if (g < lim4) xs4[t + i * 256] = xv4[g];
    }
    __syncthreads();
    const float4* W1v = (const float4*)W1;
    float4 acc[8];
#pragma unroll
    for (int i = 0; i < 8; ++i) acc[i] = make_float4(0.f, 0.f, 0.f, 0.f);
#pragma unroll 4
    for (int k = 0; k < 128; ++k) {
        float4 w = W1v[k * 32 + c];
#pragma unroll
        for (int i = 0; i < 8; ++i) {
            float xv = xs[(rg + 8 * i) * 128 + k];
            acc[i].x = fmaf(xv, w.x, acc[i].x);
            acc[i].y = fmaf(xv, w.y, acc[i].y);
            acc[i].z = fmaf(xv, w.z, acc[i].z);
            acc[i].w = fmaf(xv, w.w, acc[i].w);
        }
    }
    float4 as4 = ((const float4*)a_src)[c];
    float4 ad4 = ((const float4*)a_dst)[c];
#pragma unroll
    for (int i = 0; i < 8; ++i) {
        int n = nb + rg + 8 * i;
        if (n < N_NODES) {
            ushort4 hb;
            hb.x = bf16rn(acc[i].x); hb.y = bf16rn(acc[i].y);
            hb.z = bf16rn(acc[i].z); hb.w = bf16rn(acc[i].w);
            ((ushort4*)h1b)[(size_t)n * 32 + c] = hb;
        }
        float vs = acc[i].x * as4.x + acc[i].y * as4.y + acc[i].z * as4.z + acc[i].w * as4.w;
        float vd = acc[i].x * ad4.x + acc[i].y * ad4.y + acc[i].z * ad4.z + acc[i].w * ad4.w;
        vs += __shfl_down(vs, 4, 8); vs += __shfl_down(vs, 2, 8); vs += __shfl_down(vs, 1, 8);
        vd += __shfl_down(vd, 4, 8); vd += __shfl_down(vd, 2, 8); vd += __shfl_down(vd, 1, 8);
        if ((c & 7) == 0 && n < N_NODES) {
            int h = c >> 3;
            als[n * 4 + h] = vs;
            ald[n * 4 + h] = vd;
        }
    }
}

// ---- Layer 1 aggregation: bf16 gather, segment softmax + weighted sum ----
__global__ __launch_bounds__(128) void k_agg1(const unsigned short* __restrict__ h1b,
                                              const float* __restrict__ als,
                                              const float* __restrict__ ald,
                                              const int* __restrict__ rowptr,
                                              const int* __restrict__ col,
                                              const float* __restrict__ b1,
                                              float* __restrict__ out1) {
    int n = blockIdx.x;
    int j = threadIdx.x;
    int h = j >> 5;
    int cl = j & 31;
    __shared__ int scol[32];
    __shared__ float sex[128];
    float ad = ald[n * 4 + h];
    int beg = rowptr[n], end = rowptr[n + 1];
    float acc = 0.f, den = 0.f;
    for (int base = beg; base < end; base += 32) {
        int cnt = min(32, end - base);
        __syncthreads();
        if (j < cnt) scol[j] = col[base + j];
        __syncthreads();
        if (cl < cnt) {
            int s = scol[cl];
            sex[h * 32 + cl] = __expf(lrelu(als[s * 4 + h] + ad));
        }
        __syncthreads();
        for (int q = 0; q < cnt; ++q) {
            float ex = sex[h * 32 + q];
            int s = scol[q];
            acc = fmaf(ex, bf16tof(h1b[(size_t)s * 128 + j]), acc);
            den += ex;
        }
    }
    out1[(size_t)n * 128 + j] = fmaxf(acc / den + b1[j], 0.f);
}

// ---- Layer 2 GEMM: h2 = relu_out1 @ W2 (128x16), fused logits ----
__global__ __launch_bounds__(256) void k_gemm2(const float* __restrict__ out1,
                                               const float* __restrict__ W2,
                                               const float* __restrict__ a_src,
                                               const float* __restrict__ a_dst,
                                               float* __restrict__ h2,
                                               float* __restrict__ als,
                                               float* __restrict__ ald) {
    __shared__ float W2s[128 * 16];
    __shared__ float xs[16 * 132];
    int t = threadIdx.x;
#pragma unroll
    for (int i = 0; i < 8; ++i) W2s[t + i * 256] = W2[t + i * 256];
    size_t base = (size_t)blockIdx.x * 16 * 128;
#pragma unroll
    for (int i = 0; i < 8; ++i) {
        int idx = t + i * 256;
        xs[(idx >> 7) * 132 + (idx & 127)] = out1[base + idx];
    }
    __syncthreads();
    int r = t >> 4, c = t & 15;
    float acc = 0.f;
    const float* xr = &xs[r * 132];
#pragma unroll 8
    for (int k = 0; k < 128; ++k) acc = fmaf(xr[k], W2s[k * 16 + c], acc);
    int n = blockIdx.x * 16 + r;
    h2[(size_t)n * 16 + c] = acc;
    float vs = acc * a_src[c];
    float vd = acc * a_dst[c];
#pragma unroll
    for (int off = 8; off >= 1; off >>= 1) {
        vs += __shfl_down(vs, off, 16);
        vd += __shfl_down(vd, off, 16);
    }
    if (c == 0) { als[n] = vs; ald[n] = vd; }
}

// ---- Layer 2 aggregation ----
__global__ __launch_bounds__(256) void k_agg2(const float* __restrict__ h2,
                                              const float* __restrict__ als,
                                              const float* __restrict__ ald,
                                              const int* __restrict__ rowptr,
                                              const int* __restrict__ col,
                                              const float* __restrict__ b2,
                                              float* __restrict__ out) {
    int wave = threadIdx.x >> 6;
    int lane = threadIdx.x & 63;
    int n = blockIdx.x * 4 + wave;
    int c = lane & 15, slot = lane >> 4;
    float ad = ald[n];
    int beg = rowptr[n], end = rowptr[n + 1];
    float acc = 0.f, den = 0.f;
    for (int idx = beg + slot; idx < end; idx += 4) {
        int s = col[idx];
        float ex = __expf(lrelu(als[s] + ad));
        acc = fmaf(ex, h2[(size_t)s * 16 + c], acc);
        den += ex;
    }
    acc += __shfl_xor(acc, 16, 64); den += __shfl_xor(den, 16, 64);
    acc += __shfl_xor(acc, 32, 64); den += __shfl_xor(den, 32, 64);
    if (slot == 0) out[(size_t)n * 16 + c] = acc / den + b2[c];
}

extern "C" void kernel_launch(void* const* d_in, const int* in_sizes, int n_in,
                              void* d_out, int out_size, void* d_ws, size_t ws_size,
                              hipStream_t stream) {
    const float* x   = (const float*)d_in[0];
    const int*   ei  = (const int*)d_in[1];
    const float* W1  = (const float*)d_in[2];
    const float* as1 = (const float*)d_in[3];
    const float* ad1 = (const float*)d_in[4];
    const float* b1  = (const float*)d_in[5];
    const float* W2  = (const float*)d_in[6];
    const float* as2 = (const float*)d_in[7];
    const float* ad2 = (const float*)d_in[8];
    const float* b2  = (const float*)d_in[9];
    float* out = (float*)d_out;

    char* ws = (char*)d_ws;
    size_t off = 0;
    auto alloc = [&](size_t bytes) -> void* {
        void* p = ws + off;
        off += (bytes + 255) & ~(size_t)255;
        return p;
    };
    unsigned short* h1b = (unsigned short*)alloc((size_t)N_NODES * 128 * 2);
    float* out1  = (float*)alloc((size_t)N_NODES * 128 * 4);
    float* als1v = (float*)alloc((size_t)N_NODES * 4 * 4);
    float* ald1v = (float*)alloc((size_t)N_NODES * 4 * 4);
    float* h2    = (float*)alloc((size_t)N_NODES * 16 * 4);
    float* als2v = (float*)alloc((size_t)N_NODES * 4);
    float* ald2v = (float*)alloc((size_t)N_NODES * 4);
    int* deg     = (int*)alloc((size_t)N_NODES * 4);
    int* rowptr  = (int*)alloc((size_t)(N_NODES + 1) * 4);
    int* cursor  = (int*)alloc((size_t)N_NODES * 4);
    int* bsum    = (int*)alloc((size_t)SCAN_B * 4);
    int* colA    = (int*)alloc((size_t)E_TOT * 4);

    hipMemsetAsync(deg, 0, (size_t)N_NODES * 4, stream);
    hipMemsetAsync(cursor, 0, (size_t)N_NODES * 4, stream);

    k_deg<<<(E_TOT + 255) / 256, 256, 0, stream>>>(ei, deg);
    k_scan1<<<SCAN_B, 1024, 0, stream>>>(deg, rowptr, bsum);
    k_scan2<<<1, 128, 0, stream>>>(bsum);
    k_scan3<<<SCAN_B, 1024, 0, stream>>>(rowptr, bsum);
    k_scatter<<<(E_TOT + 255) / 256, 256, 0, stream>>>(ei, rowptr, cursor, colA);
    k_gemm1<<<(N_NODES + 63) / 64, 256, 0, stream>>>(x, W1, as1, ad1, h1b, als1v, ald1v);
    k_agg1<<<N_NODES, 128, 0, stream>>>(h1b, als1v, ald1v, rowptr, colA, b1, out1);
    k_gemm2<<<N_NODES / 16, 256, 0, stream>>>(out1, W2, as2, ad2, h2, als2v, ald2v);
    k_agg2<<<N_NODES / 4, 256, 0, stream>>>(h2, als2v, ald2v, rowptr, colA, b2, out);
}

// Round 5
// 387.521 us; speedup vs baseline: 2.1325x; 1.3289x over previous
//
#include <hip/hip_runtime.h>

#define N_NODES 100000
#define N_EDGES 1600000
#define E_TOT   (N_EDGES + N_NODES)
#define NEG_SLOPE 0.2f

#define BSH   9
#define BSZ   512                         // nodes per bucket
#define NBKT  ((N_NODES + BSZ - 1) / BSZ) // 196
#define EPB   8192                        // edges per partition block
#define PART_B ((E_TOT + EPB - 1) / EPB)  // 208

__device__ __forceinline__ float lrelu(float v) { return v > 0.f ? v : NEG_SLOPE * v; }

__device__ __forceinline__ unsigned short bf16rn(float f) {
    unsigned u = __float_as_uint(f);
    return (unsigned short)((u + 0x7FFFu + ((u >> 16) & 1u)) >> 16);
}
__device__ __forceinline__ float bf16tof(unsigned short h) {
    return __uint_as_float((unsigned)h << 16);
}

// ---- bucket histogram (LDS-aggregated) ----
__global__ __launch_bounds__(256) void k_bcount(const int* __restrict__ ei,
                                                int* __restrict__ bcnt) {
    __shared__ int lc[NBKT];
    int t = threadIdx.x;
    for (int i = t; i < NBKT; i += 256) lc[i] = 0;
    __syncthreads();
    size_t base = (size_t)blockIdx.x * EPB;
    for (int i = t; i < EPB; i += 256) {
        size_t e = base + i;
        if (e < E_TOT) {
            int d = (e < N_EDGES) ? ei[N_EDGES + e] : (int)(e - N_EDGES);
            atomicAdd(&lc[d >> BSH], 1);
        }
    }
    __syncthreads();
    for (int i = t; i < NBKT; i += 256) if (lc[i]) atomicAdd(&bcnt[i], lc[i]);
}

// ---- scan 196 bucket counts -> bases + cursors ----
__global__ __launch_bounds__(256) void k_bscan(const int* __restrict__ bcnt,
                                               int* __restrict__ bbase,
                                               int* __restrict__ gcur,
                                               int* __restrict__ rowptr) {
    int t = threadIdx.x;
    int v = (t < NBKT) ? bcnt[t] : 0;
    __shared__ int ps[256];
    ps[t] = v;
    __syncthreads();
    for (int off = 1; off < 256; off <<= 1) {
        int u = (t >= off) ? ps[t - off] : 0;
        __syncthreads();
        ps[t] += u;
        __syncthreads();
    }
    int ex = ps[t] - v;
    if (t < NBKT) { bbase[t] = ex; gcur[t] = ex; }
    if (t == 0) { bbase[NBKT] = E_TOT; rowptr[N_NODES] = E_TOT; }
}

// ---- partition edges into packed[] grouped by bucket ----
// packed = (dst & 511) << 17 | src   (src < 2^17)
__global__ __launch_bounds__(256) void k_part(const int* __restrict__ ei,
                                              int* __restrict__ gcur,
                                              int* __restrict__ packed) {
    __shared__ int lcnt[NBKT];
    __shared__ int gpos[NBKT];
    __shared__ int lcur[NBKT];
    int t = threadIdx.x;
    for (int i = t; i < NBKT; i += 256) lcnt[i] = 0;
    __syncthreads();
    size_t base = (size_t)blockIdx.x * EPB;
    for (int i = t; i < EPB; i += 256) {
        size_t e = base + i;
        if (e < E_TOT) {
            int d = (e < N_EDGES) ? ei[N_EDGES + e] : (int)(e - N_EDGES);
            atomicAdd(&lcnt[d >> BSH], 1);
        }
    }
    __syncthreads();
    for (int i = t; i < NBKT; i += 256) {
        int c = lcnt[i];
        gpos[i] = c ? atomicAdd(&gcur[i], c) : 0;
        lcur[i] = 0;
    }
    __syncthreads();
    for (int i = t; i < EPB; i += 256) {
        size_t e = base + i;
        if (e < E_TOT) {
            int s, d;
            if (e < N_EDGES) { s = ei[e]; d = ei[N_EDGES + e]; }
            else             { s = (int)(e - N_EDGES); d = s; }
            int b = d >> BSH;
            int c = atomicAdd(&lcur[b], 1);
            packed[gpos[b] + c] = ((d & (BSZ - 1)) << 17) | s;
        }
    }
}

// ---- per-bucket: local degree count+scan -> rowptr slice, then col scatter ----
__global__ __launch_bounds__(512) void k_build(const int* __restrict__ packed,
                                               const int* __restrict__ bbase,
                                               int* __restrict__ rowptr,
                                               int* __restrict__ col) {
    int t = threadIdx.x;
    int b = blockIdx.x;
    int nb = b << BSH;
    __shared__ int cnt[BSZ];
    __shared__ int ps[BSZ];
    cnt[t] = 0;
    __syncthreads();
    int ebeg = bbase[b], eend = bbase[b + 1];
    for (int i = ebeg + t; i < eend; i += 512)
        atomicAdd(&cnt[packed[i] >> 17], 1);
    __syncthreads();
    int v = cnt[t];
    ps[t] = v;
    __syncthreads();
    for (int off = 1; off < 512; off <<= 1) {
        int u = (t >= off) ? ps[t - off] : 0;
        __syncthreads();
        ps[t] += u;
        __syncthreads();
    }
    int myofs = ebeg + ps[t] - v;   // global col offset of node nb+t
    int n = nb + t;
    if (n < N_NODES) rowptr[n] = myofs;
    __syncthreads();
    cnt[t] = myofs;                  // reuse as global-position cursor
    __syncthreads();
    for (int i = ebeg + t; i < eend; i += 512) {
        int p = packed[i];
        int pos = atomicAdd(&cnt[p >> 17], 1);
        col[pos] = p & 0x1FFFF;
    }
}

// ---- Layer 1 GEMM: h1(bf16) = x @ W1, fused attention logits ----
__global__ __launch_bounds__(256) void k_gemm1(const float* __restrict__ x,
                                               const float* __restrict__ W1,
                                               const float* __restrict__ a_src,
                                               const float* __restrict__ a_dst,
                                               unsigned short* __restrict__ h1b,
                                               float* __restrict__ als,
                                               float* __restrict__ ald) {
    __shared__ float xs[64 * 128];  // 32 KB
    int t = threadIdx.x;
    int c = t & 31, rg = t >> 5;
    int nb = blockIdx.x * 64;
    const float4* xv4 = (const float4*)x;
    float4* xs4 = (float4*)xs;
    size_t base4 = (size_t)nb * 32;
    const size_t lim4 = (size_t)N_NODES * 32;
#pragma unroll
    for (int i = 0; i < 8; ++i) {
        size_t g = base4 + t + i * 256;
        if (g < lim4) xs4[t + i * 256] = xv4[g];
    }
    __syncthreads();
    const float4* W1v = (const float4*)W1;
    float4 acc[8];
#pragma unroll
    for (int i = 0; i < 8; ++i) acc[i] = make_float4(0.f, 0.f, 0.f, 0.f);
#pragma unroll 4
    for (int k = 0; k < 128; ++k) {
        float4 w = W1v[k * 32 + c];
#pragma unroll
        for (int i = 0; i < 8; ++i) {
            float xv = xs[(rg + 8 * i) * 128 + k];
            acc[i].x = fmaf(xv, w.x, acc[i].x);
            acc[i].y = fmaf(xv, w.y, acc[i].y);
            acc[i].z = fmaf(xv, w.z, acc[i].z);
            acc[i].w = fmaf(xv, w.w, acc[i].w);
        }
    }
    float4 as4 = ((const float4*)a_src)[c];
    float4 ad4 = ((const float4*)a_dst)[c];
#pragma unroll
    for (int i = 0; i < 8; ++i) {
        int n = nb + rg + 8 * i;
        if (n < N_NODES) {
            ushort4 hb;
            hb.x = bf16rn(acc[i].x); hb.y = bf16rn(acc[i].y);
            hb.z = bf16rn(acc[i].z); hb.w = bf16rn(acc[i].w);
            ((ushort4*)h1b)[(size_t)n * 32 + c] = hb;
        }
        float vs = acc[i].x * as4.x + acc[i].y * as4.y + acc[i].z * as4.z + acc[i].w * as4.w;
        float vd = acc[i].x * ad4.x + acc[i].y * ad4.y + acc[i].z * ad4.z + acc[i].w * ad4.w;
        vs += __shfl_down(vs, 4, 8); vs += __shfl_down(vs, 2, 8); vs += __shfl_down(vs, 1, 8);
        vd += __shfl_down(vd, 4, 8); vd += __shfl_down(vd, 2, 8); vd += __shfl_down(vd, 1, 8);
        if ((c & 7) == 0 && n < N_NODES) {
            int h = c >> 3;
            als[n * 4 + h] = vs;
            ald[n * 4 + h] = vd;
        }
    }
}

// ---- Layer 1 aggregation: bf16 gather, segment softmax + weighted sum ----
__global__ __launch_bounds__(128) void k_agg1(const unsigned short* __restrict__ h1b,
                                              const float* __restrict__ als,
                                              const float* __restrict__ ald,
                                              const int* __restrict__ rowptr,
                                              const int* __restrict__ col,
                                              const float* __restrict__ b1,
                                              float* __restrict__ out1) {
    int n = blockIdx.x;
    int j = threadIdx.x;
    int h = j >> 5;
    int cl = j & 31;
    __shared__ int scol[32];
    __shared__ float sex[128];
    float ad = ald[n * 4 + h];
    int beg = rowptr[n], end = rowptr[n + 1];
    float acc = 0.f, den = 0.f;
    for (int base = beg; base < end; base += 32) {
        int cnt = min(32, end - base);
        __syncthreads();
        if (j < cnt) scol[j] = col[base + j];
        __syncthreads();
        if (cl < cnt) {
            int s = scol[cl];
            sex[h * 32 + cl] = __expf(lrelu(als[s * 4 + h] + ad));
        }
        __syncthreads();
        for (int q = 0; q < cnt; ++q) {
            float ex = sex[h * 32 + q];
            int s = scol[q];
            acc = fmaf(ex, bf16tof(h1b[(size_t)s * 128 + j]), acc);
            den += ex;
        }
    }
    out1[(size_t)n * 128 + j] = fmaxf(acc / den + b1[j], 0.f);
}

// ---- Layer 2 GEMM ----
__global__ __launch_bounds__(256) void k_gemm2(const float* __restrict__ out1,
                                               const float* __restrict__ W2,
                                               const float* __restrict__ a_src,
                                               const float* __restrict__ a_dst,
                                               float* __restrict__ h2,
                                               float* __restrict__ als,
                                               float* __restrict__ ald) {
    __shared__ float W2s[128 * 16];
    __shared__ float xs[16 * 132];
    int t = threadIdx.x;
#pragma unroll
    for (int i = 0; i < 8; ++i) W2s[t + i * 256] = W2[t + i * 256];
    size_t base = (size_t)blockIdx.x * 16 * 128;
#pragma unroll
    for (int i = 0; i < 8; ++i) {
        int idx = t + i * 256;
        xs[(idx >> 7) * 132 + (idx & 127)] = out1[base + idx];
    }
    __syncthreads();
    int r = t >> 4, c = t & 15;
    float acc = 0.f;
    const float* xr = &xs[r * 132];
#pragma unroll 8
    for (int k = 0; k < 128; ++k) acc = fmaf(xr[k], W2s[k * 16 + c], acc);
    int n = blockIdx.x * 16 + r;
    h2[(size_t)n * 16 + c] = acc;
    float vs = acc * a_src[c];
    float vd = acc * a_dst[c];
#pragma unroll
    for (int off = 8; off >= 1; off >>= 1) {
        vs += __shfl_down(vs, off, 16);
        vd += __shfl_down(vd, off, 16);
    }
    if (c == 0) { als[n] = vs; ald[n] = vd; }
}

// ---- Layer 2 aggregation ----
__global__ __launch_bounds__(256) void k_agg2(const float* __restrict__ h2,
                                              const float* __restrict__ als,
                                              const float* __restrict__ ald,
                                              const int* __restrict__ rowptr,
                                              const int* __restrict__ col,
                                              const float* __restrict__ b2,
                                              float* __restrict__ out) {
    int wave = threadIdx.x >> 6;
    int lane = threadIdx.x & 63;
    int n = blockIdx.x * 4 + wave;
    int c = lane & 15, slot = lane >> 4;
    float ad = ald[n];
    int beg = rowptr[n], end = rowptr[n + 1];
    float acc = 0.f, den = 0.f;
    for (int idx = beg + slot; idx < end; idx += 4) {
        int s = col[idx];
        float ex = __expf(lrelu(als[s] + ad));
        acc = fmaf(ex, h2[(size_t)s * 16 + c], acc);
        den += ex;
    }
    acc += __shfl_xor(acc, 16, 64); den += __shfl_xor(den, 16, 64);
    acc += __shfl_xor(acc, 32, 64); den += __shfl_xor(den, 32, 64);
    if (slot == 0) out[(size_t)n * 16 + c] = acc / den + b2[c];
}

extern "C" void kernel_launch(void* const* d_in, const int* in_sizes, int n_in,
                              void* d_out, int out_size, void* d_ws, size_t ws_size,
                              hipStream_t stream) {
    const float* x   = (const float*)d_in[0];
    const int*   ei  = (const int*)d_in[1];
    const float* W1  = (const float*)d_in[2];
    const float* as1 = (const float*)d_in[3];
    const float* ad1 = (const float*)d_in[4];
    const float* b1  = (const float*)d_in[5];
    const float* W2  = (const float*)d_in[6];
    const float* as2 = (const float*)d_in[7];
    const float* ad2 = (const float*)d_in[8];
    const float* b2  = (const float*)d_in[9];
    float* out = (float*)d_out;

    char* ws = (char*)d_ws;
    size_t off = 0;
    auto alloc = [&](size_t bytes) -> void* {
        void* p = ws + off;
        off += (bytes + 255) & ~(size_t)255;
        return p;
    };
    unsigned short* h1b = (unsigned short*)alloc((size_t)N_NODES * 128 * 2);
    float* out1  = (float*)alloc((size_t)N_NODES * 128 * 4);
    float* als1v = (float*)alloc((size_t)N_NODES * 4 * 4);
    float* ald1v = (float*)alloc((size_t)N_NODES * 4 * 4);
    float* h2    = (float*)alloc((size_t)N_NODES * 16 * 4);
    float* als2v = (float*)alloc((size_t)N_NODES * 4);
    float* ald2v = (float*)alloc((size_t)N_NODES * 4);
    int* rowptr  = (int*)alloc((size_t)(N_NODES + 1) * 4);
    int* bcnt    = (int*)alloc((size_t)NBKT * 4);
    int* bbase   = (int*)alloc((size_t)(NBKT + 1) * 4);
    int* gcur    = (int*)alloc((size_t)NBKT * 4);
    int* packed  = (int*)alloc((size_t)E_TOT * 4);
    int* colA    = (int*)alloc((size_t)E_TOT * 4);

    hipMemsetAsync(bcnt, 0, (size_t)NBKT * 4, stream);

    k_bcount<<<PART_B, 256, 0, stream>>>(ei, bcnt);
    k_bscan<<<1, 256, 0, stream>>>(bcnt, bbase, gcur, rowptr);
    k_part<<<PART_B, 256, 0, stream>>>(ei, gcur, packed);
    k_build<<<NBKT, 512, 0, stream>>>(packed, bbase, rowptr, colA);
    k_gemm1<<<(N_NODES + 63) / 64, 256, 0, stream>>>(x, W1, as1, ad1, h1b, als1v, ald1v);
    k_agg1<<<N_NODES, 128, 0, stream>>>(h1b, als1v, ald1v, rowptr, colA, b1, out1);
    k_gemm2<<<N_NODES / 16, 256, 0, stream>>>(out1, W2, as2, ad2, h2, als2v, ald2v);
    k_agg2<<<N_NODES / 4, 256, 0, stream>>>(h2, als2v, ald2v, rowptr, colA, b2, out);
}

// Round 6
// 378.248 us; speedup vs baseline: 2.1848x; 1.0245x over previous
//
#include <hip/hip_runtime.h>

#define N_NODES 100000
#define N_EDGES 1600000
#define E_TOT   (N_EDGES + N_NODES)
#define NEG_SLOPE 0.2f

#define BSH   9
#define BSZ   512                         // nodes per bucket
#define NBKT  ((N_NODES + BSZ - 1) / BSZ) // 196
#define EPB   8192                        // edges per partition block
#define PART_B ((E_TOT + EPB - 1) / EPB)  // 208

__device__ __forceinline__ float lrelu(float v) { return v > 0.f ? v : NEG_SLOPE * v; }

__device__ __forceinline__ unsigned short bf16rn(float f) {
    unsigned u = __float_as_uint(f);
    return (unsigned short)((u + 0x7FFFu + ((u >> 16) & 1u)) >> 16);
}
__device__ __forceinline__ float bf16lo(unsigned u) {
    return __uint_as_float(u << 16);
}
__device__ __forceinline__ float bf16hi(unsigned u) {
    return __uint_as_float(u & 0xFFFF0000u);
}

// ---- bucket histogram (LDS-aggregated) ----
__global__ __launch_bounds__(256) void k_bcount(const int* __restrict__ ei,
                                                int* __restrict__ bcnt) {
    __shared__ int lc[NBKT];
    int t = threadIdx.x;
    for (int i = t; i < NBKT; i += 256) lc[i] = 0;
    __syncthreads();
    size_t base = (size_t)blockIdx.x * EPB;
    for (int i = t; i < EPB; i += 256) {
        size_t e = base + i;
        if (e < E_TOT) {
            int d = (e < N_EDGES) ? ei[N_EDGES + e] : (int)(e - N_EDGES);
            atomicAdd(&lc[d >> BSH], 1);
        }
    }
    __syncthreads();
    for (int i = t; i < NBKT; i += 256) if (lc[i]) atomicAdd(&bcnt[i], lc[i]);
}

// ---- scan 196 bucket counts -> bases + cursors ----
__global__ __launch_bounds__(256) void k_bscan(const int* __restrict__ bcnt,
                                               int* __restrict__ bbase,
                                               int* __restrict__ gcur,
                                               int* __restrict__ rowptr) {
    int t = threadIdx.x;
    int v = (t < NBKT) ? bcnt[t] : 0;
    __shared__ int ps[256];
    ps[t] = v;
    __syncthreads();
    for (int off = 1; off < 256; off <<= 1) {
        int u = (t >= off) ? ps[t - off] : 0;
        __syncthreads();
        ps[t] += u;
        __syncthreads();
    }
    int ex = ps[t] - v;
    if (t < NBKT) { bbase[t] = ex; gcur[t] = ex; }
    if (t == 0) { bbase[NBKT] = E_TOT; rowptr[N_NODES] = E_TOT; }
}

// ---- partition edges into packed[] grouped by bucket ----
// packed = (dst & 511) << 17 | src   (src < 2^17)
__global__ __launch_bounds__(256) void k_part(const int* __restrict__ ei,
                                              int* __restrict__ gcur,
                                              int* __restrict__ packed) {
    __shared__ int lcnt[NBKT];
    __shared__ int gpos[NBKT];
    __shared__ int lcur[NBKT];
    int t = threadIdx.x;
    for (int i = t; i < NBKT; i += 256) lcnt[i] = 0;
    __syncthreads();
    size_t base = (size_t)blockIdx.x * EPB;
    for (int i = t; i < EPB; i += 256) {
        size_t e = base + i;
        if (e < E_TOT) {
            int d = (e < N_EDGES) ? ei[N_EDGES + e] : (int)(e - N_EDGES);
            atomicAdd(&lcnt[d >> BSH], 1);
        }
    }
    __syncthreads();
    for (int i = t; i < NBKT; i += 256) {
        int c = lcnt[i];
        gpos[i] = c ? atomicAdd(&gcur[i], c) : 0;
        lcur[i] = 0;
    }
    __syncthreads();
    for (int i = t; i < EPB; i += 256) {
        size_t e = base + i;
        if (e < E_TOT) {
            int s, d;
            if (e < N_EDGES) { s = ei[e]; d = ei[N_EDGES + e]; }
            else             { s = (int)(e - N_EDGES); d = s; }
            int b = d >> BSH;
            int c = atomicAdd(&lcur[b], 1);
            packed[gpos[b] + c] = ((d & (BSZ - 1)) << 17) | s;
        }
    }
}

// ---- per-bucket: local degree count+scan -> rowptr slice, then col scatter ----
__global__ __launch_bounds__(512) void k_build(const int* __restrict__ packed,
                                               const int* __restrict__ bbase,
                                               int* __restrict__ rowptr,
                                               int* __restrict__ col) {
    int t = threadIdx.x;
    int b = blockIdx.x;
    int nb = b << BSH;
    __shared__ int cnt[BSZ];
    __shared__ int ps[BSZ];
    cnt[t] = 0;
    __syncthreads();
    int ebeg = bbase[b], eend = bbase[b + 1];
    for (int i = ebeg + t; i < eend; i += 512)
        atomicAdd(&cnt[packed[i] >> 17], 1);
    __syncthreads();
    int v = cnt[t];
    ps[t] = v;
    __syncthreads();
    for (int off = 1; off < 512; off <<= 1) {
        int u = (t >= off) ? ps[t - off] : 0;
        __syncthreads();
        ps[t] += u;
        __syncthreads();
    }
    int myofs = ebeg + ps[t] - v;   // global col offset of node nb+t
    int n = nb + t;
    if (n < N_NODES) rowptr[n] = myofs;
    __syncthreads();
    cnt[t] = myofs;                  // reuse as global-position cursor
    __syncthreads();
    for (int i = ebeg + t; i < eend; i += 512) {
        int p = packed[i];
        int pos = atomicAdd(&cnt[p >> 17], 1);
        col[pos] = p & 0x1FFFF;
    }
}

// ---- Layer 1 GEMM: h1(bf16) = x @ W1, fused attention logits ----
__global__ __launch_bounds__(256) void k_gemm1(const float* __restrict__ x,
                                               const float* __restrict__ W1,
                                               const float* __restrict__ a_src,
                                               const float* __restrict__ a_dst,
                                               unsigned short* __restrict__ h1b,
                                               float* __restrict__ als,
                                               float* __restrict__ ald) {
    __shared__ float xs[64 * 128];  // 32 KB
    int t = threadIdx.x;
    int c = t & 31, rg = t >> 5;
    int nb = blockIdx.x * 64;
    const float4* xv4 = (const float4*)x;
    float4* xs4 = (float4*)xs;
    size_t base4 = (size_t)nb * 32;
    const size_t lim4 = (size_t)N_NODES * 32;
#pragma unroll
    for (int i = 0; i < 8; ++i) {
        size_t g = base4 + t + i * 256;
        if (g < lim4) xs4[t + i * 256] = xv4[g];
    }
    __syncthreads();
    const float4* W1v = (const float4*)W1;
    float4 acc[8];
#pragma unroll
    for (int i = 0; i < 8; ++i) acc[i] = make_float4(0.f, 0.f, 0.f, 0.f);
#pragma unroll 4
    for (int k = 0; k < 128; ++k) {
        float4 w = W1v[k * 32 + c];
#pragma unroll
        for (int i = 0; i < 8; ++i) {
            float xv = xs[(rg + 8 * i) * 128 + k];
            acc[i].x = fmaf(xv, w.x, acc[i].x);
            acc[i].y = fmaf(xv, w.y, acc[i].y);
            acc[i].z = fmaf(xv, w.z, acc[i].z);
            acc[i].w = fmaf(xv, w.w, acc[i].w);
        }
    }
    float4 as4 = ((const float4*)a_src)[c];
    float4 ad4 = ((const float4*)a_dst)[c];
#pragma unroll
    for (int i = 0; i < 8; ++i) {
        int n = nb + rg + 8 * i;
        if (n < N_NODES) {
            ushort4 hb;
            hb.x = bf16rn(acc[i].x); hb.y = bf16rn(acc[i].y);
            hb.z = bf16rn(acc[i].z); hb.w = bf16rn(acc[i].w);
            ((ushort4*)h1b)[(size_t)n * 32 + c] = hb;
        }
        float vs = acc[i].x * as4.x + acc[i].y * as4.y + acc[i].z * as4.z + acc[i].w * as4.w;
        float vd = acc[i].x * ad4.x + acc[i].y * ad4.y + acc[i].z * ad4.z + acc[i].w * ad4.w;
        vs += __shfl_down(vs, 4, 8); vs += __shfl_down(vs, 2, 8); vs += __shfl_down(vs, 1, 8);
        vd += __shfl_down(vd, 4, 8); vd += __shfl_down(vd, 2, 8); vd += __shfl_down(vd, 1, 8);
        if ((c & 7) == 0 && n < N_NODES) {
            int h = c >> 3;
            als[n * 4 + h] = vs;
            ald[n * 4 + h] = vd;
        }
    }
}

// ---- Layer 1 aggregation: wave per node, half-wave per edge, 4 ch/lane ----
// lane: half=lane>>5, sub=lane&31; channels 4*sub..4*sub+3, head h=sub>>3.
// Per 64-edge chunk: lane q gathers als[s] float4, computes 4 exps, stages in
// per-wave LDS; main loop: half-waves process even/odd edges, uint2 gather of
// a full 256B h1b row per half-wave. No block barriers (waves independent).
__global__ __launch_bounds__(256) void k_agg1(const unsigned short* __restrict__ h1b,
                                              const float* __restrict__ als,
                                              const float* __restrict__ ald,
                                              const int* __restrict__ rowptr,
                                              const int* __restrict__ col,
                                              const float* __restrict__ b1,
                                              float* __restrict__ out1) {
    __shared__ float sex_all[4][64 * 4];   // 4 KB: per-wave ex[q][head]
    int w = threadIdx.x >> 6;
    int lane = threadIdx.x & 63;
    int n = blockIdx.x * 4 + w;
    int half = lane >> 5, sub = lane & 31;
    int h = sub >> 3;
    float* sex = sex_all[w];
    float4 ald4 = ((const float4*)ald)[n];
    int beg = rowptr[n], end = rowptr[n + 1];
    float a0 = 0.f, a1 = 0.f, a2 = 0.f, a3 = 0.f, den = 0.f;
    const float4* als4p = (const float4*)als;
    for (int base = beg; base < end; base += 64) {
        int cnt = min(64, end - base);
        int myc = 0;
        if (lane < cnt) myc = col[base + lane];
        // WAR: previous chunk's ds_reads must drain before overwriting sex
        __asm__ volatile("s_waitcnt lgkmcnt(0)" ::: "memory");
        if (lane < cnt) {
            float4 as4 = als4p[myc];
            float4 e4;
            e4.x = __expf(lrelu(as4.x + ald4.x));
            e4.y = __expf(lrelu(as4.y + ald4.y));
            e4.z = __expf(lrelu(as4.z + ald4.z));
            e4.w = __expf(lrelu(as4.w + ald4.w));
            ((float4*)sex)[lane] = e4;
        }
        __asm__ volatile("s_waitcnt lgkmcnt(0)" ::: "memory");
        for (int q2 = 0; q2 < cnt; q2 += 2) {
            int myq = q2 + half;
            if (myq < cnt) {
                int s = __shfl(myc, myq, 64);
                float ex = sex[myq * 4 + h];
                uint2 hv = *(const uint2*)((const char*)h1b + ((unsigned)s * 256u + sub * 8u));
                a0 = fmaf(ex, bf16lo(hv.x), a0);
                a1 = fmaf(ex, bf16hi(hv.x), a1);
                a2 = fmaf(ex, bf16lo(hv.y), a2);
                a3 = fmaf(ex, bf16hi(hv.y), a3);
                den += ex;
            }
        }
    }
    a0 += __shfl_xor(a0, 32, 64);
    a1 += __shfl_xor(a1, 32, 64);
    a2 += __shfl_xor(a2, 32, 64);
    a3 += __shfl_xor(a3, 32, 64);
    den += __shfl_xor(den, 32, 64);
    if (half == 0) {
        float4 b4 = ((const float4*)b1)[sub];
        float inv = 1.0f / den;
        float4 o;
        o.x = fmaxf(fmaf(a0, inv, b4.x), 0.f);
        o.y = fmaxf(fmaf(a1, inv, b4.y), 0.f);
        o.z = fmaxf(fmaf(a2, inv, b4.z), 0.f);
        o.w = fmaxf(fmaf(a3, inv, b4.w), 0.f);
        ((float4*)out1)[(size_t)n * 32 + sub] = o;
    }
}

// ---- Layer 2 GEMM ----
__global__ __launch_bounds__(256) void k_gemm2(const float* __restrict__ out1,
                                               const float* __restrict__ W2,
                                               const float* __restrict__ a_src,
                                               const float* __restrict__ a_dst,
                                               float* __restrict__ h2,
                                               float* __restrict__ als,
                                               float* __restrict__ ald) {
    __shared__ float W2s[128 * 16];
    __shared__ float xs[16 * 132];
    int t = threadIdx.x;
#pragma unroll
    for (int i = 0; i < 8; ++i) W2s[t + i * 256] = W2[t + i * 256];
    size_t base = (size_t)blockIdx.x * 16 * 128;
#pragma unroll
    for (int i = 0; i < 8; ++i) {
        int idx = t + i * 256;
        xs[(idx >> 7) * 132 + (idx & 127)] = out1[base + idx];
    }
    __syncthreads();
    int r = t >> 4, c = t & 15;
    float acc = 0.f;
    const float* xr = &xs[r * 132];
#pragma unroll 8
    for (int k = 0; k < 128; ++k) acc = fmaf(xr[k], W2s[k * 16 + c], acc);
    int n = blockIdx.x * 16 + r;
    h2[(size_t)n * 16 + c] = acc;
    float vs = acc * a_src[c];
    float vd = acc * a_dst[c];
#pragma unroll
    for (int off = 8; off >= 1; off >>= 1) {
        vs += __shfl_down(vs, off, 16);
        vd += __shfl_down(vd, off, 16);
    }
    if (c == 0) { als[n] = vs; ald[n] = vd; }
}

// ---- Layer 2 aggregation ----
__global__ __launch_bounds__(256) void k_agg2(const float* __restrict__ h2,
                                              const float* __restrict__ als,
                                              const float* __restrict__ ald,
                                              const int* __restrict__ rowptr,
                                              const int* __restrict__ col,
                                              const float* __restrict__ b2,
                                              float* __restrict__ out) {
    int wave = threadIdx.x >> 6;
    int lane = threadIdx.x & 63;
    int n = blockIdx.x * 4 + wave;
    int c = lane & 15, slot = lane >> 4;
    float ad = ald[n];
    int beg = rowptr[n], end = rowptr[n + 1];
    float acc = 0.f, den = 0.f;
    for (int idx = beg + slot; idx < end; idx += 4) {
        int s = col[idx];
        float ex = __expf(lrelu(als[s] + ad));
        acc = fmaf(ex, h2[(size_t)s * 16 + c], acc);
        den += ex;
    }
    acc += __shfl_xor(acc, 16, 64); den += __shfl_xor(den, 16, 64);
    acc += __shfl_xor(acc, 32, 64); den += __shfl_xor(den, 32, 64);
    if (slot == 0) out[(size_t)n * 16 + c] = acc / den + b2[c];
}

extern "C" void kernel_launch(void* const* d_in, const int* in_sizes, int n_in,
                              void* d_out, int out_size, void* d_ws, size_t ws_size,
                              hipStream_t stream) {
    const float* x   = (const float*)d_in[0];
    const int*   ei  = (const int*)d_in[1];
    const float* W1  = (const float*)d_in[2];
    const float* as1 = (const float*)d_in[3];
    const float* ad1 = (const float*)d_in[4];
    const float* b1  = (const float*)d_in[5];
    const float* W2  = (const float*)d_in[6];
    const float* as2 = (const float*)d_in[7];
    const float* ad2 = (const float*)d_in[8];
    const float* b2  = (const float*)d_in[9];
    float* out = (float*)d_out;

    char* ws = (char*)d_ws;
    size_t off = 0;
    auto alloc = [&](size_t bytes) -> void* {
        void* p = ws + off;
        off += (bytes + 255) & ~(size_t)255;
        return p;
    };
    unsigned short* h1b = (unsigned short*)alloc((size_t)N_NODES * 128 * 2);
    float* out1  = (float*)alloc((size_t)N_NODES * 128 * 4);
    float* als1v = (float*)alloc((size_t)N_NODES * 4 * 4);
    float* ald1v = (float*)alloc((size_t)N_NODES * 4 * 4);
    float* h2    = (float*)alloc((size_t)N_NODES * 16 * 4);
    float* als2v = (float*)alloc((size_t)N_NODES * 4);
    float* ald2v = (float*)alloc((size_t)N_NODES * 4);
    int* rowptr  = (int*)alloc((size_t)(N_NODES + 1) * 4);
    int* bcnt    = (int*)alloc((size_t)NBKT * 4);
    int* bbase   = (int*)alloc((size_t)(NBKT + 1) * 4);
    int* gcur    = (int*)alloc((size_t)NBKT * 4);
    int* packed  = (int*)alloc((size_t)E_TOT * 4);
    int* colA    = (int*)alloc((size_t)E_TOT * 4);

    hipMemsetAsync(bcnt, 0, (size_t)NBKT * 4, stream);

    k_bcount<<<PART_B, 256, 0, stream>>>(ei, bcnt);
    k_bscan<<<1, 256, 0, stream>>>(bcnt, bbase, gcur, rowptr);
    k_part<<<PART_B, 256, 0, stream>>>(ei, gcur, packed);
    k_build<<<NBKT, 512, 0, stream>>>(packed, bbase, rowptr, colA);
    k_gemm1<<<(N_NODES + 63) / 64, 256, 0, stream>>>(x, W1, as1, ad1, h1b, als1v, ald1v);
    k_agg1<<<N_NODES / 4, 256, 0, stream>>>(h1b, als1v, ald1v, rowptr, colA, b1, out1);
    k_gemm2<<<N_NODES / 16, 256, 0, stream>>>(out1, W2, as2, ad2, h2, als2v, ald2v);
    k_agg2<<<N_NODES / 4, 256, 0, stream>>>(h2, als2v, ald2v, rowptr, colA, b2, out);
}

// Round 7
// 363.418 us; speedup vs baseline: 2.2739x; 1.0408x over previous
//
#include <hip/hip_runtime.h>
#include <hip/hip_fp16.h>

#define N_NODES 100000
#define N_EDGES 1600000
#define E_TOT   (N_EDGES + N_NODES)
#define NEG_SLOPE 0.2f

#define BSH   9
#define BSZ   512                         // nodes per bucket
#define NBKT  ((N_NODES + BSZ - 1) / BSZ) // 196
#define EPB   8192                        // edges per partition block
#define PART_B ((E_TOT + EPB - 1) / EPB)  // 208

__device__ __forceinline__ float lrelu(float v) { return v > 0.f ? v : NEG_SLOPE * v; }

__device__ __forceinline__ float f16lo(unsigned u) {
    return __half2float(__ushort_as_half((unsigned short)(u & 0xFFFFu)));
}
__device__ __forceinline__ float f16hi(unsigned u) {
    return __half2float(__ushort_as_half((unsigned short)(u >> 16)));
}

// ---- bucket histogram (LDS-aggregated) ----
__global__ __launch_bounds__(256) void k_bcount(const int* __restrict__ ei,
                                                int* __restrict__ bcnt) {
    __shared__ int lc[NBKT];
    int t = threadIdx.x;
    for (int i = t; i < NBKT; i += 256) lc[i] = 0;
    __syncthreads();
    size_t base = (size_t)blockIdx.x * EPB;
    for (int i = t; i < EPB; i += 256) {
        size_t e = base + i;
        if (e < E_TOT) {
            int d = (e < N_EDGES) ? ei[N_EDGES + e] : (int)(e - N_EDGES);
            atomicAdd(&lc[d >> BSH], 1);
        }
    }
    __syncthreads();
    for (int i = t; i < NBKT; i += 256) if (lc[i]) atomicAdd(&bcnt[i], lc[i]);
}

// ---- scan 196 bucket counts -> bases + cursors ----
__global__ __launch_bounds__(256) void k_bscan(const int* __restrict__ bcnt,
                                               int* __restrict__ bbase,
                                               int* __restrict__ gcur,
                                               int* __restrict__ rowptr) {
    int t = threadIdx.x;
    int v = (t < NBKT) ? bcnt[t] : 0;
    __shared__ int ps[256];
    ps[t] = v;
    __syncthreads();
    for (int off = 1; off < 256; off <<= 1) {
        int u = (t >= off) ? ps[t - off] : 0;
        __syncthreads();
        ps[t] += u;
        __syncthreads();
    }
    int ex = ps[t] - v;
    if (t < NBKT) { bbase[t] = ex; gcur[t] = ex; }
    if (t == 0) { bbase[NBKT] = E_TOT; rowptr[N_NODES] = E_TOT; }
}

// ---- partition edges into packed[] grouped by bucket ----
// packed = (dst & 511) << 17 | src   (src < 2^17)
__global__ __launch_bounds__(256) void k_part(const int* __restrict__ ei,
                                              int* __restrict__ gcur,
                                              int* __restrict__ packed) {
    __shared__ int lcnt[NBKT];
    __shared__ int gpos[NBKT];
    __shared__ int lcur[NBKT];
    int t = threadIdx.x;
    for (int i = t; i < NBKT; i += 256) lcnt[i] = 0;
    __syncthreads();
    size_t base = (size_t)blockIdx.x * EPB;
    for (int i = t; i < EPB; i += 256) {
        size_t e = base + i;
        if (e < E_TOT) {
            int d = (e < N_EDGES) ? ei[N_EDGES + e] : (int)(e - N_EDGES);
            atomicAdd(&lcnt[d >> BSH], 1);
        }
    }
    __syncthreads();
    for (int i = t; i < NBKT; i += 256) {
        int c = lcnt[i];
        gpos[i] = c ? atomicAdd(&gcur[i], c) : 0;
        lcur[i] = 0;
    }
    __syncthreads();
    for (int i = t; i < EPB; i += 256) {
        size_t e = base + i;
        if (e < E_TOT) {
            int s, d;
            if (e < N_EDGES) { s = ei[e]; d = ei[N_EDGES + e]; }
            else             { s = (int)(e - N_EDGES); d = s; }
            int b = d >> BSH;
            int c = atomicAdd(&lcur[b], 1);
            packed[gpos[b] + c] = ((d & (BSZ - 1)) << 17) | s;
        }
    }
}

// ---- per-bucket: local degree count+scan -> rowptr slice, then col scatter ----
__global__ __launch_bounds__(512) void k_build(const int* __restrict__ packed,
                                               const int* __restrict__ bbase,
                                               int* __restrict__ rowptr,
                                               int* __restrict__ col) {
    int t = threadIdx.x;
    int b = blockIdx.x;
    int nb = b << BSH;
    __shared__ int cnt[BSZ];
    __shared__ int ps[BSZ];
    cnt[t] = 0;
    __syncthreads();
    int ebeg = bbase[b], eend = bbase[b + 1];
    for (int i = ebeg + t; i < eend; i += 512)
        atomicAdd(&cnt[packed[i] >> 17], 1);
    __syncthreads();
    int v = cnt[t];
    ps[t] = v;
    __syncthreads();
    for (int off = 1; off < 512; off <<= 1) {
        int u = (t >= off) ? ps[t - off] : 0;
        __syncthreads();
        ps[t] += u;
        __syncthreads();
    }
    int myofs = ebeg + ps[t] - v;   // global col offset of node nb+t
    int n = nb + t;
    if (n < N_NODES) rowptr[n] = myofs;
    __syncthreads();
    cnt[t] = myofs;                  // reuse as global-position cursor
    __syncthreads();
    for (int i = ebeg + t; i < eend; i += 512) {
        int p = packed[i];
        int pos = atomicAdd(&cnt[p >> 17], 1);
        col[pos] = p & 0x1FFFF;
    }
}

// ---- Layer 1 GEMM: h1(fp16) = x @ W1, fused attention logits ----
__global__ __launch_bounds__(256) void k_gemm1(const float* __restrict__ x,
                                               const float* __restrict__ W1,
                                               const float* __restrict__ a_src,
                                               const float* __restrict__ a_dst,
                                               unsigned short* __restrict__ h1h,
                                               float* __restrict__ als,
                                               float* __restrict__ ald) {
    __shared__ float xs[64 * 128];  // 32 KB
    int t = threadIdx.x;
    int c = t & 31, rg = t >> 5;
    int nb = blockIdx.x * 64;
    const float4* xv4 = (const float4*)x;
    float4* xs4 = (float4*)xs;
    size_t base4 = (size_t)nb * 32;
    const size_t lim4 = (size_t)N_NODES * 32;
#pragma unroll
    for (int i = 0; i < 8; ++i) {
        size_t g = base4 + t + i * 256;
        if (g < lim4) xs4[t + i * 256] = xv4[g];
    }
    __syncthreads();
    const float4* W1v = (const float4*)W1;
    float4 acc[8];
#pragma unroll
    for (int i = 0; i < 8; ++i) acc[i] = make_float4(0.f, 0.f, 0.f, 0.f);
#pragma unroll 4
    for (int k = 0; k < 128; ++k) {
        float4 w = W1v[k * 32 + c];
#pragma unroll
        for (int i = 0; i < 8; ++i) {
            float xv = xs[(rg + 8 * i) * 128 + k];
            acc[i].x = fmaf(xv, w.x, acc[i].x);
            acc[i].y = fmaf(xv, w.y, acc[i].y);
            acc[i].z = fmaf(xv, w.z, acc[i].z);
            acc[i].w = fmaf(xv, w.w, acc[i].w);
        }
    }
    float4 as4 = ((const float4*)a_src)[c];
    float4 ad4 = ((const float4*)a_dst)[c];
#pragma unroll
    for (int i = 0; i < 8; ++i) {
        int n = nb + rg + 8 * i;
        if (n < N_NODES) {
            ushort4 hb;
            hb.x = __half_as_ushort(__float2half(acc[i].x));
            hb.y = __half_as_ushort(__float2half(acc[i].y));
            hb.z = __half_as_ushort(__float2half(acc[i].z));
            hb.w = __half_as_ushort(__float2half(acc[i].w));
            ((ushort4*)h1h)[(size_t)n * 32 + c] = hb;
        }
        float vs = acc[i].x * as4.x + acc[i].y * as4.y + acc[i].z * as4.z + acc[i].w * as4.w;
        float vd = acc[i].x * ad4.x + acc[i].y * ad4.y + acc[i].z * ad4.z + acc[i].w * ad4.w;
        vs += __shfl_down(vs, 4, 8); vs += __shfl_down(vs, 2, 8); vs += __shfl_down(vs, 1, 8);
        vd += __shfl_down(vd, 4, 8); vd += __shfl_down(vd, 2, 8); vd += __shfl_down(vd, 1, 8);
        if ((c & 7) == 0 && n < N_NODES) {
            int h = c >> 3;
            als[n * 4 + h] = vs;
            ald[n * 4 + h] = vd;
        }
    }
}

// ---- Layer 1 aggregation: wave/node, 4 edges per iter, uint4 row gathers ----
// lane: slot=lane>>4 (edge within quad), cg=lane&15 (channel group: ch 8cg..8cg+7),
// head h=cg>>2. One wave-wide uint4 load = 4 full 256B h1 rows per iteration.
__global__ __launch_bounds__(256) void k_agg1(const unsigned short* __restrict__ h1h,
                                              const float* __restrict__ als,
                                              const float* __restrict__ ald,
                                              const int* __restrict__ rowptr,
                                              const int* __restrict__ col,
                                              const float* __restrict__ b1,
                                              float* __restrict__ out1) {
    __shared__ float sex_all[4][64 * 4];   // per-wave ex[q][head]
    __shared__ int   scol_all[4][64];      // per-wave col cache
    int w = threadIdx.x >> 6;
    int lane = threadIdx.x & 63;
    int n = blockIdx.x * 4 + w;
    int slot = lane >> 4, cg = lane & 15;
    int hd = cg >> 2;
    float* sex = sex_all[w];
    int* scol = scol_all[w];
    float4 ald4 = ((const float4*)ald)[n];
    int beg = rowptr[n], end = rowptr[n + 1];
    float a0 = 0.f, a1 = 0.f, a2 = 0.f, a3 = 0.f;
    float a4 = 0.f, a5 = 0.f, a6 = 0.f, a7 = 0.f, den = 0.f;
    const float4* als4p = (const float4*)als;
    for (int base = beg; base < end; base += 64) {
        int cnt = min(64, end - base);
        int myc = 0;
        if (lane < cnt) myc = col[base + lane];
        // WAR: previous chunk's ds_reads must drain before overwriting LDS
        __asm__ volatile("s_waitcnt lgkmcnt(0)" ::: "memory");
        if (lane < cnt) {
            scol[lane] = myc;
            float4 as4 = als4p[myc];
            float4 e4;
            e4.x = __expf(lrelu(as4.x + ald4.x));
            e4.y = __expf(lrelu(as4.y + ald4.y));
            e4.z = __expf(lrelu(as4.z + ald4.z));
            e4.w = __expf(lrelu(as4.w + ald4.w));
            ((float4*)sex)[lane] = e4;
        }
        __asm__ volatile("s_waitcnt lgkmcnt(0)" ::: "memory");
        for (int q4 = 0; q4 < cnt; q4 += 4) {
            int myq = q4 + slot;
            if (myq < cnt) {
                int s = scol[myq];
                float ex = sex[myq * 4 + hd];
                uint4 hv = *(const uint4*)((const char*)h1h + (((size_t)s << 8) + (cg << 4)));
                a0 = fmaf(ex, f16lo(hv.x), a0);
                a1 = fmaf(ex, f16hi(hv.x), a1);
                a2 = fmaf(ex, f16lo(hv.y), a2);
                a3 = fmaf(ex, f16hi(hv.y), a3);
                a4 = fmaf(ex, f16lo(hv.z), a4);
                a5 = fmaf(ex, f16hi(hv.z), a5);
                a6 = fmaf(ex, f16lo(hv.w), a6);
                a7 = fmaf(ex, f16hi(hv.w), a7);
                den += ex;
            }
        }
    }
    a0 += __shfl_xor(a0, 16, 64); a1 += __shfl_xor(a1, 16, 64);
    a2 += __shfl_xor(a2, 16, 64); a3 += __shfl_xor(a3, 16, 64);
    a4 += __shfl_xor(a4, 16, 64); a5 += __shfl_xor(a5, 16, 64);
    a6 += __shfl_xor(a6, 16, 64); a7 += __shfl_xor(a7, 16, 64);
    den += __shfl_xor(den, 16, 64);
    a0 += __shfl_xor(a0, 32, 64); a1 += __shfl_xor(a1, 32, 64);
    a2 += __shfl_xor(a2, 32, 64); a3 += __shfl_xor(a3, 32, 64);
    a4 += __shfl_xor(a4, 32, 64); a5 += __shfl_xor(a5, 32, 64);
    a6 += __shfl_xor(a6, 32, 64); a7 += __shfl_xor(a7, 32, 64);
    den += __shfl_xor(den, 32, 64);
    if (lane < 16) {
        float inv = 1.0f / den;
        float4 bA = ((const float4*)b1)[2 * lane];
        float4 bB = ((const float4*)b1)[2 * lane + 1];
        float4 oA, oB;
        oA.x = fmaxf(fmaf(a0, inv, bA.x), 0.f);
        oA.y = fmaxf(fmaf(a1, inv, bA.y), 0.f);
        oA.z = fmaxf(fmaf(a2, inv, bA.z), 0.f);
        oA.w = fmaxf(fmaf(a3, inv, bA.w), 0.f);
        oB.x = fmaxf(fmaf(a4, inv, bB.x), 0.f);
        oB.y = fmaxf(fmaf(a5, inv, bB.y), 0.f);
        oB.z = fmaxf(fmaf(a6, inv, bB.z), 0.f);
        oB.w = fmaxf(fmaf(a7, inv, bB.w), 0.f);
        ((float4*)out1)[(size_t)n * 32 + 2 * lane]     = oA;
        ((float4*)out1)[(size_t)n * 32 + 2 * lane + 1] = oB;
    }
}

// ---- Layer 2 GEMM ----
__global__ __launch_bounds__(256) void k_gemm2(const float* __restrict__ out1,
                                               const float* __restrict__ W2,
                                               const float* __restrict__ a_src,
                                               const float* __restrict__ a_dst,
                                               float* __restrict__ h2,
                                               float* __restrict__ als,
                                               float* __restrict__ ald) {
    __shared__ float W2s[128 * 16];
    __shared__ float xs[16 * 132];
    int t = threadIdx.x;
#pragma unroll
    for (int i = 0; i < 8; ++i) W2s[t + i * 256] = W2[t + i * 256];
    size_t base = (size_t)blockIdx.x * 16 * 128;
#pragma unroll
    for (int i = 0; i < 8; ++i) {
        int idx = t + i * 256;
        xs[(idx >> 7) * 132 + (idx & 127)] = out1[base + idx];
    }
    __syncthreads();
    int r = t >> 4, c = t & 15;
    float acc = 0.f;
    const float* xr = &xs[r * 132];
#pragma unroll 8
    for (int k = 0; k < 128; ++k) acc = fmaf(xr[k], W2s[k * 16 + c], acc);
    int n = blockIdx.x * 16 + r;
    h2[(size_t)n * 16 + c] = acc;
    float vs = acc * a_src[c];
    float vd = acc * a_dst[c];
#pragma unroll
    for (int off = 8; off >= 1; off >>= 1) {
        vs += __shfl_down(vs, off, 16);
        vd += __shfl_down(vd, off, 16);
    }
    if (c == 0) { als[n] = vs; ald[n] = vd; }
}

// ---- Layer 2 aggregation ----
__global__ __launch_bounds__(256) void k_agg2(const float* __restrict__ h2,
                                              const float* __restrict__ als,
                                              const float* __restrict__ ald,
                                              const int* __restrict__ rowptr,
                                              const int* __restrict__ col,
                                              const float* __restrict__ b2,
                                              float* __restrict__ out) {
    int wave = threadIdx.x >> 6;
    int lane = threadIdx.x & 63;
    int n = blockIdx.x * 4 + wave;
    int c = lane & 15, slot = lane >> 4;
    float ad = ald[n];
    int beg = rowptr[n], end = rowptr[n + 1];
    float acc = 0.f, den = 0.f;
    for (int idx = beg + slot; idx < end; idx += 4) {
        int s = col[idx];
        float ex = __expf(lrelu(als[s] + ad));
        acc = fmaf(ex, h2[(size_t)s * 16 + c], acc);
        den += ex;
    }
    acc += __shfl_xor(acc, 16, 64); den += __shfl_xor(den, 16, 64);
    acc += __shfl_xor(acc, 32, 64); den += __shfl_xor(den, 32, 64);
    if (slot == 0) out[(size_t)n * 16 + c] = acc / den + b2[c];
}

extern "C" void kernel_launch(void* const* d_in, const int* in_sizes, int n_in,
                              void* d_out, int out_size, void* d_ws, size_t ws_size,
                              hipStream_t stream) {
    const float* x   = (const float*)d_in[0];
    const int*   ei  = (const int*)d_in[1];
    const float* W1  = (const float*)d_in[2];
    const float* as1 = (const float*)d_in[3];
    const float* ad1 = (const float*)d_in[4];
    const float* b1  = (const float*)d_in[5];
    const float* W2  = (const float*)d_in[6];
    const float* as2 = (const float*)d_in[7];
    const float* ad2 = (const float*)d_in[8];
    const float* b2  = (const float*)d_in[9];
    float* out = (float*)d_out;

    char* ws = (char*)d_ws;
    size_t off = 0;
    auto alloc = [&](size_t bytes) -> void* {
        void* p = ws + off;
        off += (bytes + 255) & ~(size_t)255;
        return p;
    };
    unsigned short* h1h = (unsigned short*)alloc((size_t)N_NODES * 128 * 2);
    float* out1  = (float*)alloc((size_t)N_NODES * 128 * 4);
    float* als1v = (float*)alloc((size_t)N_NODES * 4 * 4);
    float* ald1v = (float*)alloc((size_t)N_NODES * 4 * 4);
    float* h2    = (float*)alloc((size_t)N_NODES * 16 * 4);
    float* als2v = (float*)alloc((size_t)N_NODES * 4);
    float* ald2v = (float*)alloc((size_t)N_NODES * 4);
    int* rowptr  = (int*)alloc((size_t)(N_NODES + 1) * 4);
    int* bcnt    = (int*)alloc((size_t)NBKT * 4);
    int* bbase   = (int*)alloc((size_t)(NBKT + 1) * 4);
    int* gcur    = (int*)alloc((size_t)NBKT * 4);
    int* packed  = (int*)alloc((size_t)E_TOT * 4);
    int* colA    = (int*)alloc((size_t)E_TOT * 4);

    hipMemsetAsync(bcnt, 0, (size_t)NBKT * 4, stream);

    k_bcount<<<PART_B, 256, 0, stream>>>(ei, bcnt);
    k_bscan<<<1, 256, 0, stream>>>(bcnt, bbase, gcur, rowptr);
    k_part<<<PART_B, 256, 0, stream>>>(ei, gcur, packed);
    k_build<<<NBKT, 512, 0, stream>>>(packed, bbase, rowptr, colA);
    k_gemm1<<<(N_NODES + 63) / 64, 256, 0, stream>>>(x, W1, as1, ad1, h1h, als1v, ald1v);
    k_agg1<<<N_NODES / 4, 256, 0, stream>>>(h1h, als1v, ald1v, rowptr, colA, b1, out1);
    k_gemm2<<<N_NODES / 16, 256, 0, stream>>>(out1, W2, as2, ad2, h2, als2v, ald2v);
    k_agg2<<<N_NODES / 4, 256, 0, stream>>>(h2, als2v, ald2v, rowptr, colA, b2, out);
}

// Round 8
// 331.718 us; speedup vs baseline: 2.4913x; 1.0956x over previous
//
#include <hip/hip_runtime.h>
#include <hip/hip_fp16.h>

#define N_NODES 100000
#define N_EDGES 1600000
#define E_TOT   (N_EDGES + N_NODES)
#define NEG_SLOPE 0.2f

#define BSH   9
#define BSZ   512                         // nodes per bucket
#define NBKT  ((N_NODES + BSZ - 1) / BSZ) // 196
#define CAP   10240                       // padded bucket capacity (mean 8673, sigma 93)
#define EPB   8192                        // edges per partition block
#define PART_B ((E_TOT + EPB - 1) / EPB)  // 208

__device__ __forceinline__ float lrelu(float v) { return v > 0.f ? v : NEG_SLOPE * v; }

__device__ __forceinline__ float f16lo(unsigned u) {
    return __half2float(__ushort_as_half((unsigned short)(u & 0xFFFFu)));
}
__device__ __forceinline__ float f16hi(unsigned u) {
    return __half2float(__ushort_as_half((unsigned short)(u >> 16)));
}

// ---- init bucket cursors to static padded bases ----
__global__ __launch_bounds__(256) void k_init(int* __restrict__ gcur) {
    int t = threadIdx.x;
    if (t < NBKT) gcur[t] = t * CAP;
}

// ---- partition edges into padded buckets ----
// packed = (dst & 511) << 17 | src   (src < 2^17)
__global__ __launch_bounds__(256) void k_part(const int* __restrict__ ei,
                                              int* __restrict__ gcur,
                                              int* __restrict__ packed) {
    __shared__ int lcnt[NBKT];
    __shared__ int gpos[NBKT];
    __shared__ int lcur[NBKT];
    int t = threadIdx.x;
    for (int i = t; i < NBKT; i += 256) lcnt[i] = 0;
    __syncthreads();
    size_t base = (size_t)blockIdx.x * EPB;
    for (int i = t; i < EPB; i += 256) {
        size_t e = base + i;
        if (e < E_TOT) {
            int d = (e < N_EDGES) ? ei[N_EDGES + e] : (int)(e - N_EDGES);
            atomicAdd(&lcnt[d >> BSH], 1);
        }
    }
    __syncthreads();
    for (int i = t; i < NBKT; i += 256) {
        int c = lcnt[i];
        gpos[i] = c ? atomicAdd(&gcur[i], c) : 0;
        lcur[i] = 0;
    }
    __syncthreads();
    for (int i = t; i < EPB; i += 256) {
        size_t e = base + i;
        if (e < E_TOT) {
            int s, d;
            if (e < N_EDGES) { s = ei[e]; d = ei[N_EDGES + e]; }
            else             { s = (int)(e - N_EDGES); d = s; }
            int b = d >> BSH;
            int c = atomicAdd(&lcur[b], 1);
            packed[gpos[b] + c] = ((d & (BSZ - 1)) << 17) | s;
        }
    }
}

// ---- per-bucket: count from cursor, local scan -> rowptr+deg, col scatter ----
__global__ __launch_bounds__(512) void k_build(const int* __restrict__ packed,
                                               const int* __restrict__ gcur,
                                               int* __restrict__ rowptr,
                                               int* __restrict__ deg,
                                               int* __restrict__ col) {
    int t = threadIdx.x;
    int b = blockIdx.x;
    int nb = b << BSH;
    int ebeg = b * CAP;
    int eend = gcur[b];
    __shared__ int cnt[BSZ];
    __shared__ int ps[BSZ];
    cnt[t] = 0;
    __syncthreads();
    for (int i = ebeg + t; i < eend; i += 512)
        atomicAdd(&cnt[packed[i] >> 17], 1);
    __syncthreads();
    int v = cnt[t];
    ps[t] = v;
    __syncthreads();
    for (int off = 1; off < 512; off <<= 1) {
        int u = (t >= off) ? ps[t - off] : 0;
        __syncthreads();
        ps[t] += u;
        __syncthreads();
    }
    int myofs = ebeg + ps[t] - v;   // padded-global col offset of node nb+t
    int n = nb + t;
    if (n < N_NODES) { rowptr[n] = myofs; deg[n] = v; }
    __syncthreads();
    cnt[t] = myofs;                  // reuse as global-position cursor
    __syncthreads();
    for (int i = ebeg + t; i < eend; i += 512) {
        int p = packed[i];
        int pos = atomicAdd(&cnt[p >> 17], 1);
        col[pos] = p & 0x1FFFF;
    }
}

// ---- Layer 1 GEMM: h1(fp16) = x @ W1, fused attention logits ----
__global__ __launch_bounds__(256) void k_gemm1(const float* __restrict__ x,
                                               const float* __restrict__ W1,
                                               const float* __restrict__ a_src,
                                               const float* __restrict__ a_dst,
                                               unsigned short* __restrict__ h1h,
                                               float* __restrict__ als,
                                               float* __restrict__ ald) {
    __shared__ float xs[64 * 128];  // 32 KB
    int t = threadIdx.x;
    int c = t & 31, rg = t >> 5;
    int nb = blockIdx.x * 64;
    const float4* xv4 = (const float4*)x;
    float4* xs4 = (float4*)xs;
    size_t base4 = (size_t)nb * 32;
    const size_t lim4 = (size_t)N_NODES * 32;
#pragma unroll
    for (int i = 0; i < 8; ++i) {
        size_t g = base4 + t + i * 256;
        if (g < lim4) xs4[t + i * 256] = xv4[g];
    }
    __syncthreads();
    const float4* W1v = (const float4*)W1;
    float4 acc[8];
#pragma unroll
    for (int i = 0; i < 8; ++i) acc[i] = make_float4(0.f, 0.f, 0.f, 0.f);
#pragma unroll 4
    for (int k = 0; k < 128; ++k) {
        float4 w = W1v[k * 32 + c];
#pragma unroll
        for (int i = 0; i < 8; ++i) {
            float xv = xs[(rg + 8 * i) * 128 + k];
            acc[i].x = fmaf(xv, w.x, acc[i].x);
            acc[i].y = fmaf(xv, w.y, acc[i].y);
            acc[i].z = fmaf(xv, w.z, acc[i].z);
            acc[i].w = fmaf(xv, w.w, acc[i].w);
        }
    }
    float4 as4 = ((const float4*)a_src)[c];
    float4 ad4 = ((const float4*)a_dst)[c];
#pragma unroll
    for (int i = 0; i < 8; ++i) {
        int n = nb + rg + 8 * i;
        if (n < N_NODES) {
            ushort4 hb;
            hb.x = __half_as_ushort(__float2half(acc[i].x));
            hb.y = __half_as_ushort(__float2half(acc[i].y));
            hb.z = __half_as_ushort(__float2half(acc[i].z));
            hb.w = __half_as_ushort(__float2half(acc[i].w));
            ((ushort4*)h1h)[(size_t)n * 32 + c] = hb;
        }
        float vs = acc[i].x * as4.x + acc[i].y * as4.y + acc[i].z * as4.z + acc[i].w * as4.w;
        float vd = acc[i].x * ad4.x + acc[i].y * ad4.y + acc[i].z * ad4.z + acc[i].w * ad4.w;
        vs += __shfl_down(vs, 4, 8); vs += __shfl_down(vs, 2, 8); vs += __shfl_down(vs, 1, 8);
        vd += __shfl_down(vd, 4, 8); vd += __shfl_down(vd, 2, 8); vd += __shfl_down(vd, 1, 8);
        if ((c & 7) == 0 && n < N_NODES) {
            int h = c >> 3;
            als[n * 4 + h] = vs;
            ald[n * 4 + h] = vd;
        }
    }
}

// ---- Layer 1 aggregation: wave/node, 4 edges/iter (unroll 2 -> 8 in flight) ----
// lane: slot=lane>>4 (edge in quad), cg=lane&15 (ch 8cg..8cg+7), head=cg>>2.
// Tail handled by clamped index + zero weight -> unconditional loads (MLP).
__global__ __launch_bounds__(256) void k_agg1(const unsigned short* __restrict__ h1h,
                                              const float* __restrict__ als,
                                              const float* __restrict__ ald,
                                              const int* __restrict__ rowptr,
                                              const int* __restrict__ deg,
                                              const int* __restrict__ col,
                                              const float* __restrict__ b1,
                                              float* __restrict__ out1) {
    __shared__ float sex_all[4][64 * 4];   // per-wave ex[q][head]
    __shared__ int   scol_all[4][64];      // per-wave col cache
    int w = threadIdx.x >> 6;
    int lane = threadIdx.x & 63;
    int n = blockIdx.x * 4 + w;
    int slot = lane >> 4, cg = lane & 15;
    int hd = cg >> 2;
    float* sex = sex_all[w];
    int* scol = scol_all[w];
    float4 ald4 = ((const float4*)ald)[n];
    int beg = rowptr[n], dtot = deg[n];
    float a0 = 0.f, a1 = 0.f, a2 = 0.f, a3 = 0.f;
    float a4 = 0.f, a5 = 0.f, a6 = 0.f, a7 = 0.f, den = 0.f;
    const float4* als4p = (const float4*)als;
    for (int base = 0; base < dtot; base += 64) {
        int cnt = min(64, dtot - base);
        int myc = 0;
        if (lane < cnt) myc = col[beg + base + lane];
        // WAR: previous chunk's ds_reads must drain before overwriting LDS
        __asm__ volatile("s_waitcnt lgkmcnt(0)" ::: "memory");
        if (lane < cnt) {
            scol[lane] = myc;
            float4 as4 = als4p[myc];
            float4 e4;
            e4.x = __expf(lrelu(as4.x + ald4.x));
            e4.y = __expf(lrelu(as4.y + ald4.y));
            e4.z = __expf(lrelu(as4.z + ald4.z));
            e4.w = __expf(lrelu(as4.w + ald4.w));
            ((float4*)sex)[lane] = e4;
        }
        __asm__ volatile("s_waitcnt lgkmcnt(0)" ::: "memory");
#pragma unroll 2
        for (int q4 = 0; q4 < cnt; q4 += 4) {
            int myq = q4 + slot;
            int cq = min(myq, cnt - 1);
            int s = scol[cq];
            float ex = (myq < cnt) ? sex[cq * 4 + hd] : 0.f;
            uint4 hv = *(const uint4*)((const char*)h1h + (((size_t)s << 8) + (cg << 4)));
            a0 = fmaf(ex, f16lo(hv.x), a0);
            a1 = fmaf(ex, f16hi(hv.x), a1);
            a2 = fmaf(ex, f16lo(hv.y), a2);
            a3 = fmaf(ex, f16hi(hv.y), a3);
            a4 = fmaf(ex, f16lo(hv.z), a4);
            a5 = fmaf(ex, f16hi(hv.z), a5);
            a6 = fmaf(ex, f16lo(hv.w), a6);
            a7 = fmaf(ex, f16hi(hv.w), a7);
            den += ex;
        }
    }
    a0 += __shfl_xor(a0, 16, 64); a1 += __shfl_xor(a1, 16, 64);
    a2 += __shfl_xor(a2, 16, 64); a3 += __shfl_xor(a3, 16, 64);
    a4 += __shfl_xor(a4, 16, 64); a5 += __shfl_xor(a5, 16, 64);
    a6 += __shfl_xor(a6, 16, 64); a7 += __shfl_xor(a7, 16, 64);
    den += __shfl_xor(den, 16, 64);
    a0 += __shfl_xor(a0, 32, 64); a1 += __shfl_xor(a1, 32, 64);
    a2 += __shfl_xor(a2, 32, 64); a3 += __shfl_xor(a3, 32, 64);
    a4 += __shfl_xor(a4, 32, 64); a5 += __shfl_xor(a5, 32, 64);
    a6 += __shfl_xor(a6, 32, 64); a7 += __shfl_xor(a7, 32, 64);
    den += __shfl_xor(den, 32, 64);
    if (lane < 16) {
        float inv = 1.0f / den;
        float4 bA = ((const float4*)b1)[2 * lane];
        float4 bB = ((const float4*)b1)[2 * lane + 1];
        float4 oA, oB;
        oA.x = fmaxf(fmaf(a0, inv, bA.x), 0.f);
        oA.y = fmaxf(fmaf(a1, inv, bA.y), 0.f);
        oA.z = fmaxf(fmaf(a2, inv, bA.z), 0.f);
        oA.w = fmaxf(fmaf(a3, inv, bA.w), 0.f);
        oB.x = fmaxf(fmaf(a4, inv, bB.x), 0.f);
        oB.y = fmaxf(fmaf(a5, inv, bB.y), 0.f);
        oB.z = fmaxf(fmaf(a6, inv, bB.z), 0.f);
        oB.w = fmaxf(fmaf(a7, inv, bB.w), 0.f);
        ((float4*)out1)[(size_t)n * 32 + 2 * lane]     = oA;
        ((float4*)out1)[(size_t)n * 32 + 2 * lane + 1] = oB;
    }
}

// ---- Layer 2 GEMM: h2(fp16) = out1 @ W2, fused logits ----
__global__ __launch_bounds__(256) void k_gemm2(const float* __restrict__ out1,
                                               const float* __restrict__ W2,
                                               const float* __restrict__ a_src,
                                               const float* __restrict__ a_dst,
                                               unsigned short* __restrict__ h2h,
                                               float* __restrict__ als,
                                               float* __restrict__ ald) {
    __shared__ float W2s[128 * 16];
    __shared__ float xs[16 * 132];
    int t = threadIdx.x;
#pragma unroll
    for (int i = 0; i < 8; ++i) W2s[t + i * 256] = W2[t + i * 256];
    size_t base = (size_t)blockIdx.x * 16 * 128;
#pragma unroll
    for (int i = 0; i < 8; ++i) {
        int idx = t + i * 256;
        xs[(idx >> 7) * 132 + (idx & 127)] = out1[base + idx];
    }
    __syncthreads();
    int r = t >> 4, c = t & 15;
    float acc = 0.f;
    const float* xr = &xs[r * 132];
#pragma unroll 8
    for (int k = 0; k < 128; ++k) acc = fmaf(xr[k], W2s[k * 16 + c], acc);
    int n = blockIdx.x * 16 + r;
    h2h[(size_t)n * 16 + c] = __half_as_ushort(__float2half(acc));
    float vs = acc * a_src[c];
    float vd = acc * a_dst[c];
#pragma unroll
    for (int off = 8; off >= 1; off >>= 1) {
        vs += __shfl_down(vs, off, 16);
        vd += __shfl_down(vd, off, 16);
    }
    if (c == 0) { als[n] = vs; ald[n] = vd; }
}

// ---- Layer 2 aggregation: wave/node, 16 edges/iter, batched exp in LDS ----
// lane: slot=lane>>2 (edge in 16-group), q=lane&3 (ch 4q..4q+3, uint2 fp16).
__global__ __launch_bounds__(256) void k_agg2(const unsigned short* __restrict__ h2h,
                                              const float* __restrict__ als,
                                              const float* __restrict__ ald,
                                              const int* __restrict__ rowptr,
                                              const int* __restrict__ deg,
                                              const int* __restrict__ col,
                                              const float* __restrict__ b2,
                                              float* __restrict__ out) {
    __shared__ float sex_all[4][64];
    __shared__ int   scol_all[4][64];
    int w = threadIdx.x >> 6;
    int lane = threadIdx.x & 63;
    int n = blockIdx.x * 4 + w;
    int slot = lane >> 2, q = lane & 3;
    float* sex = sex_all[w];
    int* scol = scol_all[w];
    float ad = ald[n];
    int beg = rowptr[n], dtot = deg[n];
    float a0 = 0.f, a1 = 0.f, a2 = 0.f, a3 = 0.f, den = 0.f;
    for (int base = 0; base < dtot; base += 64) {
        int cnt = min(64, dtot - base);
        int myc = 0;
        if (lane < cnt) myc = col[beg + base + lane];
        __asm__ volatile("s_waitcnt lgkmcnt(0)" ::: "memory");
        if (lane < cnt) {
            scol[lane] = myc;
            sex[lane] = __expf(lrelu(als[myc] + ad));
        }
        __asm__ volatile("s_waitcnt lgkmcnt(0)" ::: "memory");
#pragma unroll 2
        for (int q16 = 0; q16 < cnt; q16 += 16) {
            int myq = q16 + slot;
            int cq = min(myq, cnt - 1);
            int s = scol[cq];
            float ex = (myq < cnt) ? sex[cq] : 0.f;
            uint2 hv = *(const uint2*)((const char*)h2h + ((size_t)s * 32u + (q << 3)));
            a0 = fmaf(ex, f16lo(hv.x), a0);
            a1 = fmaf(ex, f16hi(hv.x), a1);
            a2 = fmaf(ex, f16lo(hv.y), a2);
            a3 = fmaf(ex, f16hi(hv.y), a3);
            den += ex;
        }
    }
#pragma unroll
    for (int off = 4; off <= 32; off <<= 1) {
        a0 += __shfl_xor(a0, off, 64);
        a1 += __shfl_xor(a1, off, 64);
        a2 += __shfl_xor(a2, off, 64);
        a3 += __shfl_xor(a3, off, 64);
        den += __shfl_xor(den, off, 64);
    }
    if (slot == 0) {
        float inv = 1.0f / den;
        float4 b4 = ((const float4*)b2)[q];
        float4 o;
        o.x = fmaf(a0, inv, b4.x);
        o.y = fmaf(a1, inv, b4.y);
        o.z = fmaf(a2, inv, b4.z);
        o.w = fmaf(a3, inv, b4.w);
        ((float4*)out)[(size_t)n * 4 + q] = o;
    }
}

extern "C" void kernel_launch(void* const* d_in, const int* in_sizes, int n_in,
                              void* d_out, int out_size, void* d_ws, size_t ws_size,
                              hipStream_t stream) {
    const float* x   = (const float*)d_in[0];
    const int*   ei  = (const int*)d_in[1];
    const float* W1  = (const float*)d_in[2];
    const float* as1 = (const float*)d_in[3];
    const float* ad1 = (const float*)d_in[4];
    const float* b1  = (const float*)d_in[5];
    const float* W2  = (const float*)d_in[6];
    const float* as2 = (const float*)d_in[7];
    const float* ad2 = (const float*)d_in[8];
    const float* b2  = (const float*)d_in[9];
    float* out = (float*)d_out;

    char* ws = (char*)d_ws;
    size_t off = 0;
    auto alloc = [&](size_t bytes) -> void* {
        void* p = ws + off;
        off += (bytes + 255) & ~(size_t)255;
        return p;
    };
    unsigned short* h1h = (unsigned short*)alloc((size_t)N_NODES * 128 * 2);
    float* out1  = (float*)alloc((size_t)N_NODES * 128 * 4);
    float* als1v = (float*)alloc((size_t)N_NODES * 4 * 4);
    float* ald1v = (float*)alloc((size_t)N_NODES * 4 * 4);
    unsigned short* h2h = (unsigned short*)alloc((size_t)N_NODES * 16 * 2);
    float* als2v = (float*)alloc((size_t)N_NODES * 4);
    float* ald2v = (float*)alloc((size_t)N_NODES * 4);
    int* rowptr  = (int*)alloc((size_t)N_NODES * 4);
    int* degv    = (int*)alloc((size_t)N_NODES * 4);
    int* gcur    = (int*)alloc((size_t)NBKT * 4);
    int* packed  = (int*)alloc((size_t)NBKT * CAP * 4);
    int* colA    = (int*)alloc((size_t)NBKT * CAP * 4);

    k_init<<<1, 256, 0, stream>>>(gcur);
    k_part<<<PART_B, 256, 0, stream>>>(ei, gcur, packed);
    k_build<<<NBKT, 512, 0, stream>>>(packed, gcur, rowptr, degv, colA);
    k_gemm1<<<(N_NODES + 63) / 64, 256, 0, stream>>>(x, W1, as1, ad1, h1h, als1v, ald1v);
    k_agg1<<<N_NODES / 4, 256, 0, stream>>>(h1h, als1v, ald1v, rowptr, degv, colA, b1, out1);
    k_gemm2<<<N_NODES / 16, 256, 0, stream>>>(out1, W2, as2, ad2, h2h, als2v, ald2v);
    k_agg2<<<N_NODES / 4, 256, 0, stream>>>(h2h, als2v, ald2v, rowptr, degv, colA, b2, out);
}